// Round 1
// baseline (904.836 us; speedup 1.0000x reference)
//
#include <hip/hip_runtime.h>
#include <hip/hip_bf16.h>
#include <cstdint>
#include <cstddef>

typedef __attribute__((ext_vector_type(8))) short short8;   // 8 x bf16 (4 VGPRs)
typedef __attribute__((ext_vector_type(4))) float f32x4;    // MFMA accumulator

#define DEV static __device__ __forceinline__

constexpr int kS = 1024, kD = 2048, kH = 16, kHD = 128, kF = 8192;
constexpr int kM = 4096;            // B*S rows
constexpr float kEPS = 1e-5f;

// ---------------- workspace layout (bytes) ----------------
constexpr size_t SZ_DD   = (size_t)kD * kD * 2;    // 8 MB   bf16 DxD weight
constexpr size_t SZ_FD   = (size_t)kF * kD * 2;    // 32 MB  bf16 FxD weight
constexpr size_t SZ_MD16 = (size_t)kM * kD * 2;    // 16 MB  bf16 activation
constexpr size_t SZ_MD32 = (size_t)kM * kD * 4;    // 32 MB  f32 activation
constexpr size_t OFF_WQ  = 0;
constexpr size_t OFF_WK  = OFF_WQ + SZ_DD;
constexpr size_t OFF_WV  = OFF_WK + SZ_DD;
constexpr size_t OFF_WO  = OFF_WV + SZ_DD;
constexpr size_t OFF_WI  = OFF_WO + SZ_DD;
constexpr size_t OFF_WO2 = OFF_WI + SZ_FD;
constexpr size_t OFF_XB  = OFF_WO2 + SZ_FD;        // region reused for h later
constexpr size_t OFF_Q   = OFF_XB + SZ_MD16;
constexpr size_t OFF_K   = OFF_Q + SZ_MD16;
constexpr size_t OFF_V   = OFF_K + SZ_MD16;        // holds V^T layout [bh][hd][s]
constexpr size_t OFF_H   = OFF_XB;                 // 64 MB: xb+q+k+v dead by FFN1
constexpr size_t OFF_CTX = OFF_V + SZ_MD16;
constexpr size_t OFF_Y1  = OFF_CTX + SZ_MD16;      // f32, becomes attn_out in-place
constexpr size_t OFF_A1B = OFF_Y1 + SZ_MD32;       // bf16 attn_out
constexpr size_t OFF_Y2  = OFF_A1B + SZ_MD16;      // f32
constexpr size_t WS_NEED = OFF_Y2 + SZ_MD32;       // 256 MB total

DEV void gload16(const void* g, void* l) {
  __builtin_amdgcn_global_load_lds(
      (const __attribute__((address_space(1))) unsigned int*)g,
      (__attribute__((address_space(3))) unsigned int*)l, 16, 0, 0);
}

// ---------------- fp32 -> bf16 convert ----------------
__global__ void cvt_bf16(const float* __restrict__ in, __hip_bfloat16* __restrict__ out, int n4) {
  int stride = gridDim.x * blockDim.x;
  for (int i = blockIdx.x * blockDim.x + threadIdx.x; i < n4; i += stride) {
    float4 v = reinterpret_cast<const float4*>(in)[i];
    union { ushort4 u; __hip_bfloat16 h[4]; } o;
    o.h[0] = __float2bfloat16(v.x);
    o.h[1] = __float2bfloat16(v.y);
    o.h[2] = __float2bfloat16(v.z);
    o.h[3] = __float2bfloat16(v.w);
    reinterpret_cast<ushort4*>(out)[i] = o.u;
  }
}

// ---------------- GEMM: C = A[MxK] * Bt[NxK]^T (+bias, epilogue) ----------------
// m97 structure: 128x128 tile, BK=32, 4 waves (2x2), 16x16x32 bf16 MFMA,
// global_load_lds width-16 staging, LDS slot-XOR swizzle (2-way max conflict).
// MODE 0: out bf16 scatter [b,h,s,hd]      (Q,K projections)
// MODE 4: out bf16 scatter [b,h,hd,s]      (V projection, pre-transposed for PV)
// MODE 1: out f32 = acc + bias + res       (Wo and FFN2, residual add)
// MODE 2: out bf16 = gelu(acc + bias)      (FFN1)
template <int MODE>
__global__ void gemm_bt(const __hip_bfloat16* __restrict__ A,
                        const __hip_bfloat16* __restrict__ Bt,
                        const float* __restrict__ bias,
                        const float* __restrict__ res,
                        void* __restrict__ outp,
                        int M, int N, int K) {
  __shared__ __align__(16) char As[128 * 64];   // 128 rows x 32 bf16
  __shared__ __align__(16) char Bs[128 * 64];
  const int tid = threadIdx.x;
  const int lane = tid & 63, w = tid >> 6;
  const int wr = w >> 1, wc = w & 1;
  const int lg = lane >> 4, lr = lane & 15;
  const int m0 = blockIdx.y * 128, n0 = blockIdx.x * 128;
  f32x4 acc[4][4] = {};

  for (int kt = 0; kt < K; kt += 32) {
    #pragma unroll
    for (int i = 0; i < 2; ++i) {
      int c = i * 256 + tid;
      int row = c >> 2, slot = c & 3;
      int g8 = slot ^ ((row >> 1) & 3);           // source pre-swizzle (m173 pattern)
      gload16(A + (size_t)(m0 + row) * K + kt + g8 * 8, As + c * 16);
    }
    #pragma unroll
    for (int i = 0; i < 2; ++i) {
      int c = i * 256 + tid;
      int row = c >> 2, slot = c & 3;
      int g8 = slot ^ ((row >> 1) & 3);
      gload16(Bt + (size_t)(n0 + row) * K + kt + g8 * 8, Bs + c * 16);
    }
    __syncthreads();
    short8 af[4], bfr[4];
    #pragma unroll
    for (int m = 0; m < 4; ++m) {
      int row = wr * 64 + m * 16 + lr;
      af[m] = *reinterpret_cast<const short8*>(As + row * 64 + ((lg ^ ((row >> 1) & 3)) * 16));
    }
    #pragma unroll
    for (int n = 0; n < 4; ++n) {
      int row = wc * 64 + n * 16 + lr;
      bfr[n] = *reinterpret_cast<const short8*>(Bs + row * 64 + ((lg ^ ((row >> 1) & 3)) * 16));
    }
    #pragma unroll
    for (int m = 0; m < 4; ++m)
      #pragma unroll
      for (int n = 0; n < 4; ++n)
        acc[m][n] = __builtin_amdgcn_mfma_f32_16x16x32_bf16(af[m], bfr[n], acc[m][n], 0, 0, 0);
    __syncthreads();
  }

  // epilogue: D row = wr*64+m*16+(lane>>4)*4+r, col = wc*64+n*16+(lane&15)
  #pragma unroll
  for (int n = 0; n < 4; ++n) {
    int col = n0 + wc * 64 + n * 16 + lr;
    float bv = bias[col];
    #pragma unroll
    for (int m = 0; m < 4; ++m) {
      int row0 = m0 + wr * 64 + m * 16 + lg * 4;
      #pragma unroll
      for (int r = 0; r < 4; ++r) {
        int row = row0 + r;
        float val = acc[m][n][r] + bv;
        if constexpr (MODE == 0) {
          int bb = row >> 10, ss = row & 1023, hh = col >> 7, hd = col & 127;
          ((__hip_bfloat16*)outp)[(((size_t)(bb * kH + hh)) * kS + ss) * kHD + hd] =
              __float2bfloat16(val);
        } else if constexpr (MODE == 4) {
          int bb = row >> 10, ss = row & 1023, hh = col >> 7, hd = col & 127;
          ((__hip_bfloat16*)outp)[(((size_t)(bb * kH + hh)) * kHD + hd) * kS + ss] =
              __float2bfloat16(val);
        } else if constexpr (MODE == 1) {
          size_t idx = (size_t)row * N + col;
          ((float*)outp)[idx] = val + res[idx];
        } else {  // MODE 2: exact GELU -> bf16
          float g = 0.5f * val * (1.0f + erff(val * 0.70710678118654752f));
          ((__hip_bfloat16*)outp)[(size_t)row * N + col] = __float2bfloat16(g);
        }
      }
    }
  }
}

// ---------------- flash attention ----------------
// block = 4 waves, 64 q-rows (16/wave); K-tile 64x128 and V^T-tile 128x64 in
// XOR-swizzled LDS; online softmax in registers; P staged per-wave in LDS.
__global__ void attn_fwd(const __hip_bfloat16* __restrict__ q,
                         const __hip_bfloat16* __restrict__ k,
                         const __hip_bfloat16* __restrict__ vt,
                         const float* __restrict__ mask,
                         __hip_bfloat16* __restrict__ ctx) {
  __shared__ __align__(16) char Ks[64 * 256];    // [key][dim] bf16, swz ((key&7)<<4)
  __shared__ __align__(16) char Vt[128 * 128];   // [hd][key] bf16, swz ((hd&7)<<4)
  __shared__ __align__(16) char Ps[4 * 2048];    // per-wave P [16][64] bf16, swz ((qr&7)<<4)
  const int tid = threadIdx.x, lane = tid & 63, w = tid >> 6;
  const int lg = lane >> 4, lr = lane & 15;
  const int qt = blockIdx.x, bh = blockIdx.y;
  const int b = bh >> 4, h = bh & 15;
  const int wbase = w * 2048;

  short8 qf[4];
  {
    const __hip_bfloat16* qp = q + ((size_t)bh * kS + qt * 64 + w * 16 + lr) * kHD + lg * 8;
    #pragma unroll
    for (int kk = 0; kk < 4; ++kk) qf[kk] = *reinterpret_cast<const short8*>(qp + kk * 32);
  }
  f32x4 o[8] = {};
  float mrun[4], lrun[4];
  #pragma unroll
  for (int r = 0; r < 4; ++r) { mrun[r] = -1e30f; lrun[r] = 0.f; }
  const float scale = 0.08838834764831845f;   // 1/sqrt(128)

  for (int t = 0; t < 16; ++t) {
    __syncthreads();
    #pragma unroll
    for (int i = 0; i < 4; ++i) {             // stage K rows + V^T rows, 16B each
      int c = i * 256 + tid;                  // 0..1023
      int krow = c >> 4, c16 = c & 15;
      uint4 kv = *reinterpret_cast<const uint4*>(
          k + ((size_t)bh * kS + t * 64 + krow) * kHD + c16 * 8);
      *reinterpret_cast<uint4*>(Ks + ((krow * 256 + c16 * 16) ^ ((krow & 7) << 4))) = kv;
      int hd = c >> 3, key8 = c & 7;
      uint4 vv = *reinterpret_cast<const uint4*>(
          vt + ((size_t)bh * kHD + hd) * kS + t * 64 + key8 * 8);
      *reinterpret_cast<uint4*>(Vt + ((hd * 128 + key8 * 16) ^ ((hd & 7) << 4))) = vv;
    }
    __syncthreads();

    // S = Q K^T  (A=Q rows, B=K^T: col=key, k=dim contiguous)
    f32x4 sacc[4] = {};
    #pragma unroll
    for (int j = 0; j < 4; ++j) {
      int key = j * 16 + lr;
      int kb = key * 256, sw = (key & 7) << 4;
      #pragma unroll
      for (int kk = 0; kk < 4; ++kk) {
        short8 bfrag = *reinterpret_cast<const short8*>(Ks + ((kb + kk * 64 + lg * 16) ^ sw));
        sacc[j] = __builtin_amdgcn_mfma_f32_16x16x32_bf16(qf[kk], bfrag, sacc[j], 0, 0, 0);
      }
    }
    float sarr[4][4];
    #pragma unroll
    for (int j = 0; j < 4; ++j) {
      float mv = mask[(size_t)b * kS + t * 64 + j * 16 + lr];
      #pragma unroll
      for (int r = 0; r < 4; ++r) sarr[j][r] = sacc[j][r] * scale + mv;
    }
    // online softmax: row r held by 16 lanes (same lg), butterfly over lr
    #pragma unroll
    for (int r = 0; r < 4; ++r) {
      float tm = fmaxf(fmaxf(sarr[0][r], sarr[1][r]), fmaxf(sarr[2][r], sarr[3][r]));
      #pragma unroll
      for (int d = 1; d < 16; d <<= 1) tm = fmaxf(tm, __shfl_xor(tm, d));
      float mnew = fmaxf(mrun[r], tm);
      float alpha = __expf(mrun[r] - mnew);
      mrun[r] = mnew;
      float rs = 0.f;
      #pragma unroll
      for (int j = 0; j < 4; ++j) {
        float p = __expf(sarr[j][r] - mnew);
        sarr[j][r] = p;
        rs += p;
      }
      #pragma unroll
      for (int d = 1; d < 16; d <<= 1) rs += __shfl_xor(rs, d);
      lrun[r] = lrun[r] * alpha + rs;
      #pragma unroll
      for (int n = 0; n < 8; ++n) o[n][r] *= alpha;
    }
    // P -> LDS (bf16)
    #pragma unroll
    for (int r = 0; r < 4; ++r) {
      int qr = lg * 4 + r;
      int pb = wbase + qr * 128, sw = (qr & 7) << 4;
      #pragma unroll
      for (int j = 0; j < 4; ++j)
        *reinterpret_cast<__hip_bfloat16*>(Ps + ((pb + (j * 16 + lr) * 2) ^ sw)) =
            __float2bfloat16(sarr[j][r]);
    }
    __syncthreads();
    // O += P V   (A=P rows q, k=key contiguous; B=V: col=hd, k=key contiguous)
    #pragma unroll
    for (int kk2 = 0; kk2 < 2; ++kk2) {
      short8 pa = *reinterpret_cast<const short8*>(
          Ps + ((wbase + lr * 128 + kk2 * 64 + lg * 16) ^ ((lr & 7) << 4)));
      #pragma unroll
      for (int n = 0; n < 8; ++n) {
        int hd = n * 16 + lr;
        short8 vb = *reinterpret_cast<const short8*>(
            Vt + ((hd * 128 + kk2 * 64 + lg * 16) ^ ((hd & 7) << 4)));
        o[n] = __builtin_amdgcn_mfma_f32_16x16x32_bf16(pa, vb, o[n], 0, 0, 0);
      }
    }
  }
  // ctx[b, s, h*128+hd] bf16
  #pragma unroll
  for (int r = 0; r < 4; ++r) {
    float inv = 1.0f / lrun[r];
    int srow = qt * 64 + w * 16 + lg * 4 + r;
    __hip_bfloat16* cp = ctx + ((size_t)b * kS + srow) * kD + h * 128 + lr;
    #pragma unroll
    for (int n = 0; n < 8; ++n) cp[n * 16] = __float2bfloat16(o[n][r] * inv);
  }
}

// ---------------- LayerNorm (one row of 2048 per block, 256 threads) ----------------
template <bool WB16>
__global__ void ln_row(const float* __restrict__ y, const float* __restrict__ w,
                       const float* __restrict__ b, float* __restrict__ outf,
                       __hip_bfloat16* __restrict__ outb) {
  const int row = blockIdx.x, tid = threadIdx.x;
  const float* yr = y + (size_t)row * kD;
  float v[8];
  #pragma unroll
  for (int i = 0; i < 2; ++i) {
    float4 t = reinterpret_cast<const float4*>(yr)[tid * 2 + i];
    v[i * 4 + 0] = t.x; v[i * 4 + 1] = t.y; v[i * 4 + 2] = t.z; v[i * 4 + 3] = t.w;
  }
  float s = 0.f;
  #pragma unroll
  for (int i = 0; i < 8; ++i) s += v[i];
  #pragma unroll
  for (int off = 32; off > 0; off >>= 1) s += __shfl_down(s, off);
  __shared__ float r1[4], r2[4];
  if ((tid & 63) == 0) r1[tid >> 6] = s;
  __syncthreads();
  float mean = (r1[0] + r1[1] + r1[2] + r1[3]) * (1.0f / kD);
  float qv = 0.f;
  #pragma unroll
  for (int i = 0; i < 8; ++i) { float d = v[i] - mean; qv += d * d; }
  #pragma unroll
  for (int off = 32; off > 0; off >>= 1) qv += __shfl_down(qv, off);
  if ((tid & 63) == 0) r2[tid >> 6] = qv;
  __syncthreads();
  float rstd = rsqrtf((r2[0] + r2[1] + r2[2] + r2[3]) * (1.0f / kD) + kEPS);
  #pragma unroll
  for (int i = 0; i < 8; ++i) {
    int col = tid * 8 + i;
    float ov = (v[i] - mean) * rstd * w[col] + b[col];
    outf[(size_t)row * kD + col] = ov;
    if constexpr (WB16) outb[(size_t)row * kD + col] = __float2bfloat16(ov);
  }
}

// ---------------- launcher ----------------
extern "C" void kernel_launch(void* const* d_in, const int* in_sizes, int n_in,
                              void* d_out, int out_size, void* d_ws, size_t ws_size,
                              hipStream_t stream) {
  (void)in_sizes; (void)n_in; (void)out_size;
  if (ws_size < WS_NEED) return;  // insufficient scratch: fail loudly via validation
  const float* x    = (const float*)d_in[0];
  const float* mask = (const float*)d_in[1];
  const float* wq   = (const float*)d_in[2];
  const float* bq   = (const float*)d_in[3];
  const float* wk   = (const float*)d_in[4];
  const float* bk   = (const float*)d_in[5];
  const float* wv   = (const float*)d_in[6];
  const float* bv   = (const float*)d_in[7];
  const float* wo   = (const float*)d_in[8];
  const float* bo   = (const float*)d_in[9];
  const float* l1w  = (const float*)d_in[10];
  const float* l1b  = (const float*)d_in[11];
  const float* wi   = (const float*)d_in[12];
  const float* bi   = (const float*)d_in[13];
  const float* wo2  = (const float*)d_in[14];
  const float* bo2  = (const float*)d_in[15];
  const float* l2w  = (const float*)d_in[16];
  const float* l2b  = (const float*)d_in[17];

  char* ws = (char*)d_ws;
  __hip_bfloat16* wqb  = (__hip_bfloat16*)(ws + OFF_WQ);
  __hip_bfloat16* wkb  = (__hip_bfloat16*)(ws + OFF_WK);
  __hip_bfloat16* wvb  = (__hip_bfloat16*)(ws + OFF_WV);
  __hip_bfloat16* wob  = (__hip_bfloat16*)(ws + OFF_WO);
  __hip_bfloat16* wib  = (__hip_bfloat16*)(ws + OFF_WI);
  __hip_bfloat16* wo2b = (__hip_bfloat16*)(ws + OFF_WO2);
  __hip_bfloat16* xb   = (__hip_bfloat16*)(ws + OFF_XB);
  __hip_bfloat16* qb   = (__hip_bfloat16*)(ws + OFF_Q);
  __hip_bfloat16* kb2  = (__hip_bfloat16*)(ws + OFF_K);
  __hip_bfloat16* vtb  = (__hip_bfloat16*)(ws + OFF_V);
  __hip_bfloat16* hb   = (__hip_bfloat16*)(ws + OFF_H);
  __hip_bfloat16* ctxb = (__hip_bfloat16*)(ws + OFF_CTX);
  __hip_bfloat16* a1b  = (__hip_bfloat16*)(ws + OFF_A1B);
  float* y1 = (float*)(ws + OFF_Y1);
  float* y2 = (float*)(ws + OFF_Y2);

  // fp32 -> bf16 conversions
  cvt_bf16<<<2048, 256, 0, stream>>>(x,   xb,   kM * kD / 4);
  cvt_bf16<<<1024, 256, 0, stream>>>(wq,  wqb,  kD * kD / 4);
  cvt_bf16<<<1024, 256, 0, stream>>>(wk,  wkb,  kD * kD / 4);
  cvt_bf16<<<1024, 256, 0, stream>>>(wv,  wvb,  kD * kD / 4);
  cvt_bf16<<<1024, 256, 0, stream>>>(wo,  wob,  kD * kD / 4);
  cvt_bf16<<<2048, 256, 0, stream>>>(wi,  wib,  kF * kD / 4);
  cvt_bf16<<<2048, 256, 0, stream>>>(wo2, wo2b, kF * kD / 4);

  dim3 blk(256);
  dim3 gDD(kD / 128, kM / 128);
  dim3 gDF(kF / 128, kM / 128);
  // QKV projections (V written pre-transposed)
  gemm_bt<0><<<gDD, blk, 0, stream>>>(xb, wqb, bq, nullptr, qb,  kM, kD, kD);
  gemm_bt<0><<<gDD, blk, 0, stream>>>(xb, wkb, bk, nullptr, kb2, kM, kD, kD);
  gemm_bt<4><<<gDD, blk, 0, stream>>>(xb, wvb, bv, nullptr, vtb, kM, kD, kD);
  // attention
  attn_fwd<<<dim3(kS / 64, 64), blk, 0, stream>>>(qb, kb2, vtb, mask, ctxb);
  // out proj + residual, LN1 (in-place + bf16 copy)
  gemm_bt<1><<<gDD, blk, 0, stream>>>(ctxb, wob, bo, x, y1, kM, kD, kD);
  ln_row<true><<<kM, 256, 0, stream>>>(y1, l1w, l1b, y1, a1b);
  // FFN
  gemm_bt<2><<<gDF, blk, 0, stream>>>(a1b, wib, bi, nullptr, hb, kM, kF, kD);
  gemm_bt<1><<<gDD, blk, 0, stream>>>(hb, wo2b, bo2, y1, y2, kM, kD, kF);
  ln_row<false><<<kM, 256, 0, stream>>>(y2, l2w, l2b, (float*)d_out, nullptr);
}

// Round 2
// 771.760 us; speedup vs baseline: 1.1724x; 1.1724x over previous
//
#include <hip/hip_runtime.h>
#include <hip/hip_bf16.h>
#include <cstdint>
#include <cstddef>

typedef __attribute__((ext_vector_type(8))) short short8;   // 8 x bf16 (4 VGPRs)
typedef __attribute__((ext_vector_type(4))) float f32x4;    // MFMA accumulator

#define DEV static __device__ __forceinline__

constexpr int kS = 1024, kD = 2048, kH = 16, kHD = 128, kF = 8192;
constexpr int kM = 4096;            // B*S rows
constexpr float kEPS = 1e-5f;

// ---------------- workspace layout (bytes) ----------------
constexpr size_t SZ_DD   = (size_t)kD * kD * 2;    // 8 MB   bf16 DxD weight
constexpr size_t SZ_FD   = (size_t)kF * kD * 2;    // 32 MB  bf16 FxD weight
constexpr size_t SZ_MD16 = (size_t)kM * kD * 2;    // 16 MB  bf16 activation
constexpr size_t SZ_MD32 = (size_t)kM * kD * 4;    // 32 MB  f32 activation
constexpr size_t OFF_WQ  = 0;                      // wq/wk/wv contiguous => fused QKV weight
constexpr size_t OFF_WK  = OFF_WQ + SZ_DD;
constexpr size_t OFF_WV  = OFF_WK + SZ_DD;
constexpr size_t OFF_WO  = OFF_WV + SZ_DD;
constexpr size_t OFF_WI  = OFF_WO + SZ_DD;
constexpr size_t OFF_WO2 = OFF_WI + SZ_FD;
constexpr size_t OFF_XB  = OFF_WO2 + SZ_FD;        // region reused for h later
constexpr size_t OFF_Q   = OFF_XB + SZ_MD16;       // q/k/vt contiguous (fused epilogue)
constexpr size_t OFF_K   = OFF_Q + SZ_MD16;
constexpr size_t OFF_V   = OFF_K + SZ_MD16;        // holds V^T layout [bh][hd][s]
constexpr size_t OFF_H   = OFF_XB;                 // 64 MB: xb+q+k+v dead by FFN1
constexpr size_t OFF_CTX = OFF_V + SZ_MD16;
constexpr size_t OFF_Y1  = OFF_CTX + SZ_MD16;      // f32, becomes attn_out in-place
constexpr size_t OFF_A1B = OFF_Y1 + SZ_MD32;       // bf16 attn_out
constexpr size_t OFF_Y2  = OFF_A1B + SZ_MD16;      // f32 (first 24KB doubles as bqkv early)
constexpr size_t WS_NEED = OFF_Y2 + SZ_MD32;       // 256 MB total

DEV void gload16(const void* g, void* l) {
  __builtin_amdgcn_global_load_lds(
      (const __attribute__((address_space(1))) unsigned int*)g,
      (__attribute__((address_space(3))) unsigned int*)l, 16, 0, 0);
}

// ---------------- fp32 -> bf16 convert ----------------
__global__ void cvt_bf16(const float* __restrict__ in, __hip_bfloat16* __restrict__ out, int n4) {
  int stride = gridDim.x * blockDim.x;
  for (int i = blockIdx.x * blockDim.x + threadIdx.x; i < n4; i += stride) {
    float4 v = reinterpret_cast<const float4*>(in)[i];
    union { ushort4 u; __hip_bfloat16 h[4]; } o;
    o.h[0] = __float2bfloat16(v.x);
    o.h[1] = __float2bfloat16(v.y);
    o.h[2] = __float2bfloat16(v.z);
    o.h[3] = __float2bfloat16(v.w);
    reinterpret_cast<ushort4*>(out)[i] = o.u;
  }
}

// ---------------- GEMM: C = A[MxK] * Bt[NxK]^T (+bias, epilogue) ----------------
// 128x128 tile, BK=64 (one barrier pair per 64-K), 4 waves, 16x16x32 bf16 MFMA,
// global_load_lds width-16 staging with slot^(row&7) swizzle, XCD-chunked grid.
// MODE 0: fused QKV scatter: q/k -> [b,h,s,hd], v -> [b,h,hd,s] (outp = q base)
// MODE 1: out f32 = acc + bias + res
// MODE 2: out bf16 = gelu(acc + bias)
template <int MODE>
__global__ void gemm_bt(const __hip_bfloat16* __restrict__ A,
                        const __hip_bfloat16* __restrict__ Bt,
                        const float* __restrict__ bias,
                        const float* __restrict__ res,
                        void* __restrict__ outp,
                        int M, int N, int K) {
  __shared__ __align__(16) char As[128 * 128];   // 128 rows x 64 bf16
  __shared__ __align__(16) char Bs[128 * 128];
  const int tid = threadIdx.x;
  const int lane = tid & 63, w = tid >> 6;
  const int wr = w >> 1, wc = w & 1;
  const int lg = lane >> 4, lr = lane & 15;
  // bijective XCD-chunked swizzle (all grids divisible by 8); n-panel-major
  const int nwg = gridDim.x, orig = blockIdx.x;
  const int l = (orig & 7) * (nwg >> 3) + (orig >> 3);
  const int gy = M >> 7;
  const int bx = l / gy, by = l - bx * gy;
  const int m0 = by * 128, n0 = bx * 128;
  f32x4 acc[4][4] = {};

  for (int kt = 0; kt < K; kt += 64) {
    #pragma unroll
    for (int i = 0; i < 4; ++i) {
      int c = i * 256 + tid;
      int row = c >> 3, slot = c & 7;
      int g8 = slot ^ (row & 7);                  // pre-swizzled global source
      gload16(A + (size_t)(m0 + row) * K + kt + g8 * 8, As + c * 16);
    }
    #pragma unroll
    for (int i = 0; i < 4; ++i) {
      int c = i * 256 + tid;
      int row = c >> 3, slot = c & 7;
      int g8 = slot ^ (row & 7);
      gload16(Bt + (size_t)(n0 + row) * K + kt + g8 * 8, Bs + c * 16);
    }
    __syncthreads();
    #pragma unroll
    for (int kk = 0; kk < 2; ++kk) {
      short8 af[4], bfr[4];
      #pragma unroll
      for (int m = 0; m < 4; ++m) {
        int row = wr * 64 + m * 16 + lr;
        af[m] = *reinterpret_cast<const short8*>(
            As + row * 128 + (((kk * 4 + lg) ^ (row & 7)) * 16));
      }
      #pragma unroll
      for (int n = 0; n < 4; ++n) {
        int row = wc * 64 + n * 16 + lr;
        bfr[n] = *reinterpret_cast<const short8*>(
            Bs + row * 128 + (((kk * 4 + lg) ^ (row & 7)) * 16));
      }
      #pragma unroll
      for (int m = 0; m < 4; ++m)
        #pragma unroll
        for (int n = 0; n < 4; ++n)
          acc[m][n] = __builtin_amdgcn_mfma_f32_16x16x32_bf16(af[m], bfr[n], acc[m][n], 0, 0, 0);
    }
    __syncthreads();
  }

  // epilogue: D row = wr*64+m*16+lg*4+r, col = wc*64+n*16+lr
  #pragma unroll
  for (int n = 0; n < 4; ++n) {
    int col = n0 + wc * 64 + n * 16 + lr;
    float bv = bias[col];
    #pragma unroll
    for (int m = 0; m < 4; ++m) {
      int row0 = m0 + wr * 64 + m * 16 + lg * 4;
      #pragma unroll
      for (int r = 0; r < 4; ++r) {
        int row = row0 + r;
        float val = acc[m][n][r] + bv;
        if constexpr (MODE == 0) {
          int which = col >> 11;                  // 0=q 1=k 2=v (uniform per n-iter)
          int d = col & 2047;
          int hh = d >> 7, hd = d & 127;
          int bb = row >> 10, ss = row & 1023;
          __hip_bfloat16* base = (__hip_bfloat16*)outp + (size_t)which * ((size_t)kM * kD);
          if (which < 2)
            base[(((size_t)(bb * kH + hh)) * kS + ss) * kHD + hd] = __float2bfloat16(val);
          else
            base[(((size_t)(bb * kH + hh)) * kHD + hd) * kS + ss] = __float2bfloat16(val);
        } else if constexpr (MODE == 1) {
          size_t idx = (size_t)row * N + col;
          ((float*)outp)[idx] = val + res[idx];
        } else {  // MODE 2: exact GELU -> bf16
          float g = 0.5f * val * (1.0f + erff(val * 0.70710678118654752f));
          ((__hip_bfloat16*)outp)[(size_t)row * N + col] = __float2bfloat16(g);
        }
      }
    }
  }
}

// ---------------- flash attention v2 ----------------
// 8 waves, 128 q-rows/block (16/wave); KV tile 64 keys; double-buffered K/V in
// LDS via global_load_lds (pre-swizzled source, swizzled ds_read); 2-phase
// pipeline: STAGE(next) -> compute -> one barrier per tile. XCD-chunked grid
// (8 bh per XCD -> K/V working set 4MB = L2).
__global__ __launch_bounds__(512, 4)
void attn_fwd(const __hip_bfloat16* __restrict__ q,
              const __hip_bfloat16* __restrict__ k,
              const __hip_bfloat16* __restrict__ vt,
              const float* __restrict__ mask,
              __hip_bfloat16* __restrict__ ctx) {
  __shared__ __align__(16) char Ks[2][64 * 256];    // [buf][key][dim] slot16^(row&15)
  __shared__ __align__(16) char Vt[2][128 * 128];   // [buf][hd][key64] slot8^(row&7)
  __shared__ __align__(16) char Ps[8][2048];        // per-wave P [16][64], ^((row&7)<<4)
  const int tid = threadIdx.x, lane = tid & 63, w = tid >> 6;
  const int lg = lane >> 4, lr = lane & 15;
  const int orig = blockIdx.x;                      // 512 blocks
  const int l = (orig & 7) * 64 + (orig >> 3);      // XCD-chunked: 8 bh per XCD
  const int qt = l & 7, bh = l >> 3;
  const int b = bh >> 4;

  short8 qf[4];
  {
    const __hip_bfloat16* qp =
        q + ((size_t)bh * kS + qt * 128 + w * 16 + lr) * kHD + lg * 8;
    #pragma unroll
    for (int kk = 0; kk < 4; ++kk) qf[kk] = *reinterpret_cast<const short8*>(qp + kk * 32);
  }

  auto stage = [&](int bufi, int t) {
    #pragma unroll
    for (int i = 0; i < 2; ++i) {                   // K tile: 64 rows x 256B
      int c = i * 512 + tid;
      int row = c >> 4, slot = c & 15;
      gload16(k + ((size_t)bh * kS + t * 64 + row) * kHD + (slot ^ (row & 15)) * 8,
              Ks[bufi] + c * 16);
    }
    #pragma unroll
    for (int i = 0; i < 2; ++i) {                   // V^T tile: 128 rows x 128B
      int c = i * 512 + tid;
      int row = c >> 3, slot = c & 7;
      gload16(vt + ((size_t)bh * kHD + row) * kS + t * 64 + (slot ^ (row & 7)) * 8,
              Vt[bufi] + c * 16);
    }
  };

  f32x4 o[8] = {};
  float mrun[4], lrun[4];
  #pragma unroll
  for (int r = 0; r < 4; ++r) { mrun[r] = -1e30f; lrun[r] = 0.f; }
  const float scale = 0.08838834764831845f;         // 1/sqrt(128)

  stage(0, 0);
  __syncthreads();                                  // drains vmcnt(0)

  int buf = 0;
  for (int t = 0; t < 16; ++t) {
    if (t + 1 < 16) stage(buf ^ 1, t + 1);          // async prefetch next tile

    // S = Q K^T
    f32x4 sacc[4] = {};
    #pragma unroll
    for (int j = 0; j < 4; ++j) {
      int key = j * 16 + lr;
      #pragma unroll
      for (int kk = 0; kk < 4; ++kk) {
        short8 bfrag = *reinterpret_cast<const short8*>(
            Ks[buf] + key * 256 + (((kk * 4 + lg) ^ (key & 15)) * 16));
        sacc[j] = __builtin_amdgcn_mfma_f32_16x16x32_bf16(qf[kk], bfrag, sacc[j], 0, 0, 0);
      }
    }
    float sarr[4][4];
    #pragma unroll
    for (int j = 0; j < 4; ++j) {
      float mv = mask[(size_t)b * kS + t * 64 + j * 16 + lr];
      #pragma unroll
      for (int r = 0; r < 4; ++r) sarr[j][r] = sacc[j][r] * scale + mv;
    }
    // online softmax: row r held by 16 lanes (same lg), butterfly over lr
    #pragma unroll
    for (int r = 0; r < 4; ++r) {
      float tm = fmaxf(fmaxf(sarr[0][r], sarr[1][r]), fmaxf(sarr[2][r], sarr[3][r]));
      #pragma unroll
      for (int d = 1; d < 16; d <<= 1) tm = fmaxf(tm, __shfl_xor(tm, d));
      float mnew = fmaxf(mrun[r], tm);
      float alpha = __expf(mrun[r] - mnew);
      mrun[r] = mnew;
      float rs = 0.f;
      #pragma unroll
      for (int j = 0; j < 4; ++j) {
        float p = __expf(sarr[j][r] - mnew);
        sarr[j][r] = p;
        rs += p;
      }
      #pragma unroll
      for (int d = 1; d < 16; d <<= 1) rs += __shfl_xor(rs, d);
      lrun[r] = lrun[r] * alpha + rs;
      #pragma unroll
      for (int n = 0; n < 8; ++n) o[n][r] *= alpha;
    }
    // P -> per-wave LDS (bf16); wave-local, no barrier needed
    #pragma unroll
    for (int r = 0; r < 4; ++r) {
      int qr = lg * 4 + r;
      #pragma unroll
      for (int j = 0; j < 4; ++j)
        *reinterpret_cast<__hip_bfloat16*>(
            Ps[w] + ((qr * 128 + (j * 16 + lr) * 2) ^ ((qr & 7) << 4))) =
            __float2bfloat16(sarr[j][r]);
    }
    // O += P V
    #pragma unroll
    for (int kk2 = 0; kk2 < 2; ++kk2) {
      short8 pa = *reinterpret_cast<const short8*>(
          Ps[w] + ((lr * 128 + kk2 * 64 + lg * 16) ^ ((lr & 7) << 4)));
      #pragma unroll
      for (int n = 0; n < 8; ++n) {
        int hd = n * 16 + lr;
        short8 vb = *reinterpret_cast<const short8*>(
            Vt[buf] + hd * 128 + (((kk2 * 4 + lg) ^ (hd & 7)) * 16));
        o[n] = __builtin_amdgcn_mfma_f32_16x16x32_bf16(pa, vb, o[n], 0, 0, 0);
      }
    }
    __syncthreads();   // all waves done with buf; staged buf^1 complete (vmcnt drain)
    buf ^= 1;
  }

  // ctx[b, s, h*128+hd] bf16
  const int h = bh & 15;
  #pragma unroll
  for (int r = 0; r < 4; ++r) {
    float inv = 1.0f / lrun[r];
    int srow = qt * 128 + w * 16 + lg * 4 + r;
    __hip_bfloat16* cp = ctx + ((size_t)b * kS + srow) * kD + h * 128 + lr;
    #pragma unroll
    for (int n = 0; n < 8; ++n) cp[n * 16] = __float2bfloat16(o[n][r] * inv);
  }
}

// ---------------- LayerNorm (one row of 2048 per block, 256 threads) ----------------
template <bool WB16>
__global__ void ln_row(const float* __restrict__ y, const float* __restrict__ w,
                       const float* __restrict__ b, float* __restrict__ outf,
                       __hip_bfloat16* __restrict__ outb) {
  const int row = blockIdx.x, tid = threadIdx.x;
  const float* yr = y + (size_t)row * kD;
  float v[8];
  #pragma unroll
  for (int i = 0; i < 2; ++i) {
    float4 t = reinterpret_cast<const float4*>(yr)[tid * 2 + i];
    v[i * 4 + 0] = t.x; v[i * 4 + 1] = t.y; v[i * 4 + 2] = t.z; v[i * 4 + 3] = t.w;
  }
  float s = 0.f;
  #pragma unroll
  for (int i = 0; i < 8; ++i) s += v[i];
  #pragma unroll
  for (int off = 32; off > 0; off >>= 1) s += __shfl_down(s, off);
  __shared__ float r1[4], r2[4];
  if ((tid & 63) == 0) r1[tid >> 6] = s;
  __syncthreads();
  float mean = (r1[0] + r1[1] + r1[2] + r1[3]) * (1.0f / kD);
  float qv = 0.f;
  #pragma unroll
  for (int i = 0; i < 8; ++i) { float d = v[i] - mean; qv += d * d; }
  #pragma unroll
  for (int off = 32; off > 0; off >>= 1) qv += __shfl_down(qv, off);
  if ((tid & 63) == 0) r2[tid >> 6] = qv;
  __syncthreads();
  float rstd = rsqrtf((r2[0] + r2[1] + r2[2] + r2[3]) * (1.0f / kD) + kEPS);
  #pragma unroll
  for (int i = 0; i < 8; ++i) {
    int col = tid * 8 + i;
    float ov = (v[i] - mean) * rstd * w[col] + b[col];
    outf[(size_t)row * kD + col] = ov;
    if constexpr (WB16) outb[(size_t)row * kD + col] = __float2bfloat16(ov);
  }
}

// ---------------- launcher ----------------
extern "C" void kernel_launch(void* const* d_in, const int* in_sizes, int n_in,
                              void* d_out, int out_size, void* d_ws, size_t ws_size,
                              hipStream_t stream) {
  (void)in_sizes; (void)n_in; (void)out_size;
  if (ws_size < WS_NEED) return;
  const float* x    = (const float*)d_in[0];
  const float* mask = (const float*)d_in[1];
  const float* wq   = (const float*)d_in[2];
  const float* bq   = (const float*)d_in[3];
  const float* wk   = (const float*)d_in[4];
  const float* bk   = (const float*)d_in[5];
  const float* wv   = (const float*)d_in[6];
  const float* bv   = (const float*)d_in[7];
  const float* wo   = (const float*)d_in[8];
  const float* bo   = (const float*)d_in[9];
  const float* l1w  = (const float*)d_in[10];
  const float* l1b  = (const float*)d_in[11];
  const float* wi   = (const float*)d_in[12];
  const float* bi   = (const float*)d_in[13];
  const float* wo2  = (const float*)d_in[14];
  const float* bo2  = (const float*)d_in[15];
  const float* l2w  = (const float*)d_in[16];
  const float* l2b  = (const float*)d_in[17];

  char* ws = (char*)d_ws;
  __hip_bfloat16* wqb  = (__hip_bfloat16*)(ws + OFF_WQ);   // fused QKV weight base
  __hip_bfloat16* wkb  = (__hip_bfloat16*)(ws + OFF_WK);
  __hip_bfloat16* wvb  = (__hip_bfloat16*)(ws + OFF_WV);
  __hip_bfloat16* wob  = (__hip_bfloat16*)(ws + OFF_WO);
  __hip_bfloat16* wib  = (__hip_bfloat16*)(ws + OFF_WI);
  __hip_bfloat16* wo2b = (__hip_bfloat16*)(ws + OFF_WO2);
  __hip_bfloat16* xb   = (__hip_bfloat16*)(ws + OFF_XB);
  __hip_bfloat16* qb   = (__hip_bfloat16*)(ws + OFF_Q);    // q/k/vt contiguous
  __hip_bfloat16* kb2  = (__hip_bfloat16*)(ws + OFF_K);
  __hip_bfloat16* vtb  = (__hip_bfloat16*)(ws + OFF_V);
  __hip_bfloat16* hb   = (__hip_bfloat16*)(ws + OFF_H);
  __hip_bfloat16* ctxb = (__hip_bfloat16*)(ws + OFF_CTX);
  __hip_bfloat16* a1b  = (__hip_bfloat16*)(ws + OFF_A1B);
  float* y1   = (float*)(ws + OFF_Y1);
  float* y2   = (float*)(ws + OFF_Y2);
  float* bqkv = (float*)(ws + OFF_Y2);   // 24KB concat bias; dead before FFN2 writes y2

  // fp32 -> bf16 conversions
  cvt_bf16<<<2048, 256, 0, stream>>>(x,   xb,   kM * kD / 4);
  cvt_bf16<<<1024, 256, 0, stream>>>(wq,  wqb,  kD * kD / 4);
  cvt_bf16<<<1024, 256, 0, stream>>>(wk,  wkb,  kD * kD / 4);
  cvt_bf16<<<1024, 256, 0, stream>>>(wv,  wvb,  kD * kD / 4);
  cvt_bf16<<<1024, 256, 0, stream>>>(wo,  wob,  kD * kD / 4);
  cvt_bf16<<<2048, 256, 0, stream>>>(wi,  wib,  kF * kD / 4);
  cvt_bf16<<<2048, 256, 0, stream>>>(wo2, wo2b, kF * kD / 4);
  // concat QKV bias into scratch
  hipMemcpyAsync(bqkv,        bq, kD * 4, hipMemcpyDeviceToDevice, stream);
  hipMemcpyAsync(bqkv + kD,   bk, kD * 4, hipMemcpyDeviceToDevice, stream);
  hipMemcpyAsync(bqkv + 2*kD, bv, kD * 4, hipMemcpyDeviceToDevice, stream);

  dim3 blk(256);
  // fused QKV projection: M=4096, N=6144, K=2048
  gemm_bt<0><<<dim3((6144 / 128) * (kM / 128)), blk, 0, stream>>>(
      xb, wqb, bqkv, nullptr, qb, kM, 6144, kD);
  // attention
  attn_fwd<<<dim3(512), dim3(512), 0, stream>>>(qb, kb2, vtb, mask, ctxb);
  // out proj + residual, LN1 (in-place + bf16 copy)
  gemm_bt<1><<<dim3((kD / 128) * (kM / 128)), blk, 0, stream>>>(
      ctxb, wob, bo, x, y1, kM, kD, kD);
  ln_row<true><<<kM, 256, 0, stream>>>(y1, l1w, l1b, y1, a1b);
  // FFN
  gemm_bt<2><<<dim3((kF / 128) * (kM / 128)), blk, 0, stream>>>(
      a1b, wib, bi, nullptr, hb, kM, kF, kD);
  gemm_bt<1><<<dim3((kD / 128) * (kM / 128)), blk, 0, stream>>>(
      hb, wo2b, bo2, y1, y2, kM, kD, kF);
  ln_row<false><<<kM, 256, 0, stream>>>(y2, l2w, l2b, (float*)d_out, nullptr);
}

// Round 3
// 751.329 us; speedup vs baseline: 1.2043x; 1.0272x over previous
//
#include <hip/hip_runtime.h>
#include <hip/hip_bf16.h>
#include <cstdint>
#include <cstddef>

typedef __attribute__((ext_vector_type(8))) short short8;   // 8 x bf16 (4 VGPRs)
typedef __attribute__((ext_vector_type(4))) float f32x4;    // MFMA accumulator

#define DEV static __device__ __forceinline__

constexpr int kS = 1024, kD = 2048, kH = 16, kHD = 128, kF = 8192;
constexpr int kM = 4096;            // B*S rows
constexpr float kEPS = 1e-5f;

// ---------------- workspace layout (bytes) ----------------
constexpr size_t SZ_DD   = (size_t)kD * kD * 2;    // 8 MB   bf16 DxD weight
constexpr size_t SZ_FD   = (size_t)kF * kD * 2;    // 32 MB  bf16 FxD weight
constexpr size_t SZ_MD16 = (size_t)kM * kD * 2;    // 16 MB  bf16 activation
constexpr size_t SZ_MD32 = (size_t)kM * kD * 4;    // 32 MB  f32 activation
constexpr size_t OFF_WQ  = 0;                      // wq/wk/wv contiguous => fused QKV weight
constexpr size_t OFF_WK  = OFF_WQ + SZ_DD;
constexpr size_t OFF_WV  = OFF_WK + SZ_DD;
constexpr size_t OFF_WO  = OFF_WV + SZ_DD;
constexpr size_t OFF_WI  = OFF_WO + SZ_DD;
constexpr size_t OFF_WO2 = OFF_WI + SZ_FD;
constexpr size_t OFF_XB  = OFF_WO2 + SZ_FD;        // region reused for h later
constexpr size_t OFF_Q   = OFF_XB + SZ_MD16;       // q/k/vt contiguous (fused epilogue)
constexpr size_t OFF_K   = OFF_Q + SZ_MD16;
constexpr size_t OFF_V   = OFF_K + SZ_MD16;        // holds V^T layout [bh][hd][s]
constexpr size_t OFF_H   = OFF_XB;                 // 64 MB: xb+q+k+v dead by FFN1
constexpr size_t OFF_CTX = OFF_V + SZ_MD16;
constexpr size_t OFF_Y1  = OFF_CTX + SZ_MD16;      // f32
constexpr size_t OFF_A1B = OFF_Y1 + SZ_MD32;       // bf16 attn_out
constexpr size_t OFF_Y2  = OFF_A1B + SZ_MD16;      // f32 (first 24KB doubles as bqkv early)
constexpr size_t WS_NEED = OFF_Y2 + SZ_MD32;       // 256 MB total
// FFN2 second split-K partial reuses dead wq..wo region (4 x 8MB = 32MB) at OFF_WQ.

DEV void gload16(const void* g, void* l) {
  __builtin_amdgcn_global_load_lds(
      (const __attribute__((address_space(1))) unsigned int*)g,
      (__attribute__((address_space(3))) unsigned int*)l, 16, 0, 0);
}

// ---------------- fp32 -> bf16 convert ----------------
__global__ void cvt_bf16(const float* __restrict__ in, __hip_bfloat16* __restrict__ out, int n4) {
  int stride = gridDim.x * blockDim.x;
  for (int i = blockIdx.x * blockDim.x + threadIdx.x; i < n4; i += stride) {
    float4 v = reinterpret_cast<const float4*>(in)[i];
    union { ushort4 u; __hip_bfloat16 h[4]; } o;
    o.h[0] = __float2bfloat16(v.x);
    o.h[1] = __float2bfloat16(v.y);
    o.h[2] = __float2bfloat16(v.z);
    o.h[3] = __float2bfloat16(v.w);
    reinterpret_cast<ushort4*>(out)[i] = o.u;
  }
}

// ---------------- 256x256 8-phase deep-pipelined GEMM ----------------
// C = A[MxK] * Bt[NxK]^T. BK=64, 8 waves (2M x 4N), 128 KiB LDS double-buffer.
// Per K-tile: 4 phases (one C-quadrant each, 16 MFMA), each phase issues one
// half-tile global_load_lds prefetch of tile t+1; raw s_barrier pairs; counted
// drain: single vmcnt(0) per K-tile covering loads issued 1-4 phases earlier.
// MODE 0: fused QKV scatter (q/k -> [b,h,s,hd], v -> [b,h,hd,s]), outb = q base
// MODE 2: out bf16 = gelu(acc + bias) at [row*N+col], outb
// MODE 3: raw f32 partial (split-K): out0/out1 selected by split index
template <int MODE>
__global__ __launch_bounds__(512, 2)
void gemm256(const __hip_bfloat16* __restrict__ A,
             const __hip_bfloat16* __restrict__ Bt,
             const float* __restrict__ bias,
             float* __restrict__ out0, float* __restrict__ out1,
             void* __restrict__ outb,
             int M, int N, int K, int kLen) {
  __shared__ __align__(16) char lds[131072];   // A: [2][256][64]b16 @0, B: @65536
  const int tid = threadIdx.x;
  const int lane = tid & 63, w = tid >> 6;
  const int wm = w >> 2, wn = w & 3;
  const int lg = lane >> 4, lr = lane & 15;
  const int gy = M >> 8, gx = N >> 8;
  const int nwg = gridDim.x, orig = blockIdx.x;
  const int l = (orig & 7) * (nwg >> 3) + (orig >> 3);   // XCD-chunked (nwg%8==0)
  const int tilesPer = gx * gy;
  const int spl = l / tilesPer;
  const int rem = l - spl * tilesPer;
  const int bx = rem / gy, by = rem - bx * gy;           // n-panel-major
  const int m0 = by * 256, n0 = bx * 256;
  const int k0 = spl * kLen;
  const int NT = kLen >> 6;

  auto stageHalf = [&](int p, int half, int t) {
    // half: 0 = A rows 0-127, 1 = A rows 128-255, 2 = B rows 0-127, 3 = B rows 128-255
    const __hip_bfloat16* src = (half < 2) ? A : Bt;
    const int r0 = ((half < 2) ? m0 : n0) + (half & 1) * 128;
    char* dst = lds + ((half < 2) ? 0 : 65536) + p * 32768 + (half & 1) * 16384;
    const int kt = k0 + t * 64;
    #pragma unroll
    for (int i = 0; i < 2; ++i) {
      int c = i * 512 + tid;
      int row = c >> 3, slot = c & 7;
      gload16(src + (size_t)(r0 + row) * K + kt + (slot ^ (row & 7)) * 8, dst + c * 16);
    }
  };
  auto ldA = [&](int p, int mr, int kk) {
    int row = wm * 128 + mr * 16 + lr;
    return *reinterpret_cast<const short8*>(
        lds + p * 32768 + row * 128 + (((kk * 4 + lg) ^ (row & 7)) * 16));
  };
  auto ldB = [&](int p, int nr, int kk) {
    int row = wn * 64 + nr * 16 + lr;
    return *reinterpret_cast<const short8*>(
        lds + 65536 + p * 32768 + row * 128 + (((kk * 4 + lg) ^ (row & 7)) * 16));
  };

  f32x4 acc[8][4] = {};

  stageHalf(0, 0, 0); stageHalf(0, 1, 0); stageHalf(0, 2, 0); stageHalf(0, 3, 0);
  asm volatile("s_waitcnt vmcnt(0)" ::: "memory");
  __builtin_amdgcn_s_barrier();

  for (int t = 0; t < NT; ++t) {
    const int p = t & 1;
    const bool pf = (t + 1 < NT);
    short8 av[2][4], bv[2][2];

    // ---- P0: quadrant (mh=0, nh=0) — 12 ds_reads
    #pragma unroll
    for (int i = 0; i < 4; ++i) { av[0][i] = ldA(p, i, 0); av[1][i] = ldA(p, i, 1); }
    #pragma unroll
    for (int i = 0; i < 2; ++i) { bv[0][i] = ldB(p, i, 0); bv[1][i] = ldB(p, i, 1); }
    if (pf) stageHalf(p ^ 1, 0, t + 1);
    __builtin_amdgcn_s_barrier();
    asm volatile("s_waitcnt lgkmcnt(0)" ::: "memory");
    __builtin_amdgcn_sched_barrier(0);
    __builtin_amdgcn_s_setprio(1);
    #pragma unroll
    for (int kk = 0; kk < 2; ++kk)
      #pragma unroll
      for (int mi = 0; mi < 4; ++mi)
        #pragma unroll
        for (int ni = 0; ni < 2; ++ni)
          acc[mi][ni] = __builtin_amdgcn_mfma_f32_16x16x32_bf16(av[kk][mi], bv[kk][ni], acc[mi][ni], 0, 0, 0);
    __builtin_amdgcn_s_setprio(0);
    __builtin_amdgcn_s_barrier();

    // ---- P1: quadrant (mh=1, nh=0) — reuse bv, 8 ds_reads
    #pragma unroll
    for (int i = 0; i < 4; ++i) { av[0][i] = ldA(p, 4 + i, 0); av[1][i] = ldA(p, 4 + i, 1); }
    if (pf) stageHalf(p ^ 1, 1, t + 1);
    __builtin_amdgcn_s_barrier();
    asm volatile("s_waitcnt lgkmcnt(0)" ::: "memory");
    __builtin_amdgcn_sched_barrier(0);
    __builtin_amdgcn_s_setprio(1);
    #pragma unroll
    for (int kk = 0; kk < 2; ++kk)
      #pragma unroll
      for (int mi = 0; mi < 4; ++mi)
        #pragma unroll
        for (int ni = 0; ni < 2; ++ni)
          acc[4 + mi][ni] = __builtin_amdgcn_mfma_f32_16x16x32_bf16(av[kk][mi], bv[kk][ni], acc[4 + mi][ni], 0, 0, 0);
    __builtin_amdgcn_s_setprio(0);
    __builtin_amdgcn_s_barrier();

    // ---- P2: quadrant (mh=1, nh=1) — reuse av, 4 ds_reads
    #pragma unroll
    for (int i = 0; i < 2; ++i) { bv[0][i] = ldB(p, 2 + i, 0); bv[1][i] = ldB(p, 2 + i, 1); }
    if (pf) stageHalf(p ^ 1, 2, t + 1);
    __builtin_amdgcn_s_barrier();
    asm volatile("s_waitcnt lgkmcnt(0)" ::: "memory");
    __builtin_amdgcn_sched_barrier(0);
    __builtin_amdgcn_s_setprio(1);
    #pragma unroll
    for (int kk = 0; kk < 2; ++kk)
      #pragma unroll
      for (int mi = 0; mi < 4; ++mi)
        #pragma unroll
        for (int ni = 0; ni < 2; ++ni)
          acc[4 + mi][2 + ni] = __builtin_amdgcn_mfma_f32_16x16x32_bf16(av[kk][mi], bv[kk][ni], acc[4 + mi][2 + ni], 0, 0, 0);
    __builtin_amdgcn_s_setprio(0);
    __builtin_amdgcn_s_barrier();

    // ---- P3: quadrant (mh=0, nh=1) — reuse bv, 8 ds_reads; tile-boundary drain
    #pragma unroll
    for (int i = 0; i < 4; ++i) { av[0][i] = ldA(p, i, 0); av[1][i] = ldA(p, i, 1); }
    if (pf) stageHalf(p ^ 1, 3, t + 1);
    __builtin_amdgcn_s_barrier();
    asm volatile("s_waitcnt lgkmcnt(0)" ::: "memory");
    __builtin_amdgcn_sched_barrier(0);
    __builtin_amdgcn_s_setprio(1);
    #pragma unroll
    for (int kk = 0; kk < 2; ++kk)
      #pragma unroll
      for (int mi = 0; mi < 4; ++mi)
        #pragma unroll
        for (int ni = 0; ni < 2; ++ni)
          acc[mi][2 + ni] = __builtin_amdgcn_mfma_f32_16x16x32_bf16(av[kk][mi], bv[kk][ni], acc[mi][2 + ni], 0, 0, 0);
    __builtin_amdgcn_s_setprio(0);
    asm volatile("s_waitcnt vmcnt(0)" ::: "memory");   // tile t+1 fully staged
    __builtin_amdgcn_s_barrier();
  }

  // epilogue: row = m0+wm*128+mr*16+lg*4+r, col = n0+wn*64+nr*16+lr
  #pragma unroll
  for (int nr = 0; nr < 4; ++nr) {
    int col = n0 + wn * 64 + nr * 16 + lr;
    float bvv = 0.f;
    if constexpr (MODE != 3) bvv = bias[col];
    #pragma unroll
    for (int mr = 0; mr < 8; ++mr) {
      int row0 = m0 + wm * 128 + mr * 16 + lg * 4;
      #pragma unroll
      for (int r = 0; r < 4; ++r) {
        int row = row0 + r;
        float val = acc[mr][nr][r] + bvv;
        if constexpr (MODE == 0) {
          int which = col >> 11;                  // 0=q 1=k 2=v
          int d = col & 2047;
          int hh = d >> 7, hd = d & 127;
          int bb = row >> 10, ss = row & 1023;
          __hip_bfloat16* base = (__hip_bfloat16*)outb + (size_t)which * ((size_t)kM * kD);
          if (which < 2)
            base[(((size_t)(bb * kH + hh)) * kS + ss) * kHD + hd] = __float2bfloat16(val);
          else
            base[(((size_t)(bb * kH + hh)) * kHD + hd) * kS + ss] = __float2bfloat16(val);
        } else if constexpr (MODE == 2) {
          float g = 0.5f * val * (1.0f + erff(val * 0.70710678118654752f));
          ((__hip_bfloat16*)outb)[(size_t)row * N + col] = __float2bfloat16(g);
        } else {
          float* o = spl ? out1 : out0;
          o[(size_t)row * N + col] = val;
        }
      }
    }
  }
}

// ---------------- flash attention (unchanged from round 1) ----------------
__global__ __launch_bounds__(512, 4)
void attn_fwd(const __hip_bfloat16* __restrict__ q,
              const __hip_bfloat16* __restrict__ k,
              const __hip_bfloat16* __restrict__ vt,
              const float* __restrict__ mask,
              __hip_bfloat16* __restrict__ ctx) {
  __shared__ __align__(16) char Ks[2][64 * 256];    // [buf][key][dim] slot16^(row&15)
  __shared__ __align__(16) char Vt[2][128 * 128];   // [buf][hd][key64] slot8^(row&7)
  __shared__ __align__(16) char Ps[8][2048];        // per-wave P [16][64], ^((row&7)<<4)
  const int tid = threadIdx.x, lane = tid & 63, w = tid >> 6;
  const int lg = lane >> 4, lr = lane & 15;
  const int orig = blockIdx.x;                      // 512 blocks
  const int l = (orig & 7) * 64 + (orig >> 3);      // XCD-chunked: 8 bh per XCD
  const int qt = l & 7, bh = l >> 3;
  const int b = bh >> 4;

  short8 qf[4];
  {
    const __hip_bfloat16* qp =
        q + ((size_t)bh * kS + qt * 128 + w * 16 + lr) * kHD + lg * 8;
    #pragma unroll
    for (int kk = 0; kk < 4; ++kk) qf[kk] = *reinterpret_cast<const short8*>(qp + kk * 32);
  }

  auto stage = [&](int bufi, int t) {
    #pragma unroll
    for (int i = 0; i < 2; ++i) {                   // K tile: 64 rows x 256B
      int c = i * 512 + tid;
      int row = c >> 4, slot = c & 15;
      gload16(k + ((size_t)bh * kS + t * 64 + row) * kHD + (slot ^ (row & 15)) * 8,
              Ks[bufi] + c * 16);
    }
    #pragma unroll
    for (int i = 0; i < 2; ++i) {                   // V^T tile: 128 rows x 128B
      int c = i * 512 + tid;
      int row = c >> 3, slot = c & 7;
      gload16(vt + ((size_t)bh * kHD + row) * kS + t * 64 + (slot ^ (row & 7)) * 8,
              Vt[bufi] + c * 16);
    }
  };

  f32x4 o[8] = {};
  float mrun[4], lrun[4];
  #pragma unroll
  for (int r = 0; r < 4; ++r) { mrun[r] = -1e30f; lrun[r] = 0.f; }
  const float scale = 0.08838834764831845f;         // 1/sqrt(128)

  stage(0, 0);
  __syncthreads();

  int buf = 0;
  for (int t = 0; t < 16; ++t) {
    if (t + 1 < 16) stage(buf ^ 1, t + 1);

    f32x4 sacc[4] = {};
    #pragma unroll
    for (int j = 0; j < 4; ++j) {
      int key = j * 16 + lr;
      #pragma unroll
      for (int kk = 0; kk < 4; ++kk) {
        short8 bfrag = *reinterpret_cast<const short8*>(
            Ks[buf] + key * 256 + (((kk * 4 + lg) ^ (key & 15)) * 16));
        sacc[j] = __builtin_amdgcn_mfma_f32_16x16x32_bf16(qf[kk], bfrag, sacc[j], 0, 0, 0);
      }
    }
    float sarr[4][4];
    #pragma unroll
    for (int j = 0; j < 4; ++j) {
      float mv = mask[(size_t)b * kS + t * 64 + j * 16 + lr];
      #pragma unroll
      for (int r = 0; r < 4; ++r) sarr[j][r] = sacc[j][r] * scale + mv;
    }
    #pragma unroll
    for (int r = 0; r < 4; ++r) {
      float tm = fmaxf(fmaxf(sarr[0][r], sarr[1][r]), fmaxf(sarr[2][r], sarr[3][r]));
      #pragma unroll
      for (int d = 1; d < 16; d <<= 1) tm = fmaxf(tm, __shfl_xor(tm, d));
      float mnew = fmaxf(mrun[r], tm);
      float alpha = __expf(mrun[r] - mnew);
      mrun[r] = mnew;
      float rs = 0.f;
      #pragma unroll
      for (int j = 0; j < 4; ++j) {
        float p = __expf(sarr[j][r] - mnew);
        sarr[j][r] = p;
        rs += p;
      }
      #pragma unroll
      for (int d = 1; d < 16; d <<= 1) rs += __shfl_xor(rs, d);
      lrun[r] = lrun[r] * alpha + rs;
      #pragma unroll
      for (int n = 0; n < 8; ++n) o[n][r] *= alpha;
    }
    #pragma unroll
    for (int r = 0; r < 4; ++r) {
      int qr = lg * 4 + r;
      #pragma unroll
      for (int j = 0; j < 4; ++j)
        *reinterpret_cast<__hip_bfloat16*>(
            Ps[w] + ((qr * 128 + (j * 16 + lr) * 2) ^ ((qr & 7) << 4))) =
            __float2bfloat16(sarr[j][r]);
    }
    #pragma unroll
    for (int kk2 = 0; kk2 < 2; ++kk2) {
      short8 pa = *reinterpret_cast<const short8*>(
          Ps[w] + ((lr * 128 + kk2 * 64 + lg * 16) ^ ((lr & 7) << 4)));
      #pragma unroll
      for (int n = 0; n < 8; ++n) {
        int hd = n * 16 + lr;
        short8 vb = *reinterpret_cast<const short8*>(
            Vt[buf] + hd * 128 + (((kk2 * 4 + lg) ^ (hd & 7)) * 16));
        o[n] = __builtin_amdgcn_mfma_f32_16x16x32_bf16(pa, vb, o[n], 0, 0, 0);
      }
    }
    __syncthreads();
    buf ^= 1;
  }

  const int h = bh & 15;
  #pragma unroll
  for (int r = 0; r < 4; ++r) {
    float inv = 1.0f / lrun[r];
    int srow = qt * 128 + w * 16 + lg * 4 + r;
    __hip_bfloat16* cp = ctx + ((size_t)b * kS + srow) * kD + h * 128 + lr;
    #pragma unroll
    for (int n = 0; n < 8; ++n) cp[n * 16] = __float2bfloat16(o[n][r] * inv);
  }
}

// ------- LayerNorm over (p0 + p1 + bias + res), one 2048-row per block -------
template <bool WB16>
__global__ void ln_fuse(const float* __restrict__ p0, const float* __restrict__ p1,
                        const float* __restrict__ bias, const float* __restrict__ res,
                        const float* __restrict__ w, const float* __restrict__ b,
                        float* __restrict__ outf, __hip_bfloat16* __restrict__ outb) {
  const int row = blockIdx.x, tid = threadIdx.x;
  const size_t base = (size_t)row * kD;
  float v[8];
  #pragma unroll
  for (int i = 0; i < 2; ++i) {
    int c4 = tid * 2 + i;
    float4 a  = reinterpret_cast<const float4*>(p0 + base)[c4];
    float4 bb = reinterpret_cast<const float4*>(p1 + base)[c4];
    float4 rr = reinterpret_cast<const float4*>(res + base)[c4];
    float4 bs = reinterpret_cast<const float4*>(bias)[c4];
    v[i * 4 + 0] = a.x + bb.x + rr.x + bs.x;
    v[i * 4 + 1] = a.y + bb.y + rr.y + bs.y;
    v[i * 4 + 2] = a.z + bb.z + rr.z + bs.z;
    v[i * 4 + 3] = a.w + bb.w + rr.w + bs.w;
  }
  float s = 0.f;
  #pragma unroll
  for (int i = 0; i < 8; ++i) s += v[i];
  #pragma unroll
  for (int off = 32; off > 0; off >>= 1) s += __shfl_down(s, off);
  __shared__ float r1[4], r2[4];
  if ((tid & 63) == 0) r1[tid >> 6] = s;
  __syncthreads();
  float mean = (r1[0] + r1[1] + r1[2] + r1[3]) * (1.0f / kD);
  float qv = 0.f;
  #pragma unroll
  for (int i = 0; i < 8; ++i) { float d = v[i] - mean; qv += d * d; }
  #pragma unroll
  for (int off = 32; off > 0; off >>= 1) qv += __shfl_down(qv, off);
  if ((tid & 63) == 0) r2[tid >> 6] = qv;
  __syncthreads();
  float rstd = rsqrtf((r2[0] + r2[1] + r2[2] + r2[3]) * (1.0f / kD) + kEPS);
  #pragma unroll
  for (int i = 0; i < 8; ++i) {
    int col = tid * 8 + i;
    float ov = (v[i] - mean) * rstd * w[col] + b[col];
    outf[base + col] = ov;
    if constexpr (WB16) outb[base + col] = __float2bfloat16(ov);
  }
}

// ---------------- launcher ----------------
extern "C" void kernel_launch(void* const* d_in, const int* in_sizes, int n_in,
                              void* d_out, int out_size, void* d_ws, size_t ws_size,
                              hipStream_t stream) {
  (void)in_sizes; (void)n_in; (void)out_size;
  if (ws_size < WS_NEED) return;
  const float* x    = (const float*)d_in[0];
  const float* mask = (const float*)d_in[1];
  const float* wq   = (const float*)d_in[2];
  const float* bq   = (const float*)d_in[3];
  const float* wk   = (const float*)d_in[4];
  const float* bk   = (const float*)d_in[5];
  const float* wv   = (const float*)d_in[6];
  const float* bv   = (const float*)d_in[7];
  const float* wo   = (const float*)d_in[8];
  const float* bo   = (const float*)d_in[9];
  const float* l1w  = (const float*)d_in[10];
  const float* l1b  = (const float*)d_in[11];
  const float* wi   = (const float*)d_in[12];
  const float* bi   = (const float*)d_in[13];
  const float* wo2  = (const float*)d_in[14];
  const float* bo2  = (const float*)d_in[15];
  const float* l2w  = (const float*)d_in[16];
  const float* l2b  = (const float*)d_in[17];

  char* ws = (char*)d_ws;
  __hip_bfloat16* wqb  = (__hip_bfloat16*)(ws + OFF_WQ);   // fused QKV weight base
  __hip_bfloat16* wkb  = (__hip_bfloat16*)(ws + OFF_WK);
  __hip_bfloat16* wvb  = (__hip_bfloat16*)(ws + OFF_WV);
  __hip_bfloat16* wob  = (__hip_bfloat16*)(ws + OFF_WO);
  __hip_bfloat16* wib  = (__hip_bfloat16*)(ws + OFF_WI);
  __hip_bfloat16* wo2b = (__hip_bfloat16*)(ws + OFF_WO2);
  __hip_bfloat16* xb   = (__hip_bfloat16*)(ws + OFF_XB);
  __hip_bfloat16* qb   = (__hip_bfloat16*)(ws + OFF_Q);    // q/k/vt contiguous
  __hip_bfloat16* kb2  = (__hip_bfloat16*)(ws + OFF_K);
  __hip_bfloat16* vtb  = (__hip_bfloat16*)(ws + OFF_V);
  __hip_bfloat16* hb   = (__hip_bfloat16*)(ws + OFF_H);
  __hip_bfloat16* ctxb = (__hip_bfloat16*)(ws + OFF_CTX);
  __hip_bfloat16* a1b  = (__hip_bfloat16*)(ws + OFF_A1B);
  float* y1   = (float*)(ws + OFF_Y1);
  float* y2   = (float*)(ws + OFF_Y2);
  float* f2p  = (float*)(ws + OFF_WQ);   // FFN2 split-K partial 1 (32MB, weights dead)
  float* bqkv = (float*)(ws + OFF_Y2);   // 24KB concat bias; dead before Wo writes y2

  // fp32 -> bf16 conversions
  cvt_bf16<<<2048, 256, 0, stream>>>(x,   xb,   kM * kD / 4);
  cvt_bf16<<<1024, 256, 0, stream>>>(wq,  wqb,  kD * kD / 4);
  cvt_bf16<<<1024, 256, 0, stream>>>(wk,  wkb,  kD * kD / 4);
  cvt_bf16<<<1024, 256, 0, stream>>>(wv,  wvb,  kD * kD / 4);
  cvt_bf16<<<1024, 256, 0, stream>>>(wo,  wob,  kD * kD / 4);
  cvt_bf16<<<2048, 256, 0, stream>>>(wi,  wib,  kF * kD / 4);
  cvt_bf16<<<2048, 256, 0, stream>>>(wo2, wo2b, kF * kD / 4);
  // concat QKV bias into scratch
  hipMemcpyAsync(bqkv,          bq, kD * 4, hipMemcpyDeviceToDevice, stream);
  hipMemcpyAsync(bqkv + kD,     bk, kD * 4, hipMemcpyDeviceToDevice, stream);
  hipMemcpyAsync(bqkv + 2 * kD, bv, kD * 4, hipMemcpyDeviceToDevice, stream);

  dim3 blk(512);
  // fused QKV projection: M=4096, N=6144, K=2048 -> grid 24*16 = 384
  gemm256<0><<<dim3(384), blk, 0, stream>>>(
      xb, wqb, bqkv, nullptr, nullptr, qb, kM, 6144, kD, kD);
  // attention
  attn_fwd<<<dim3(512), dim3(512), 0, stream>>>(qb, kb2, vtb, mask, ctxb);
  // out proj, split-K x2 (grid 2*8*16 = 256), partials y1,y2; LN1 fuses +bo+x
  gemm256<3><<<dim3(256), blk, 0, stream>>>(
      ctxb, wob, nullptr, y1, y2, nullptr, kM, kD, kD, kD / 2);
  ln_fuse<true><<<kM, 256, 0, stream>>>(y1, y2, bo, x, l1w, l1b, y1, a1b);
  // FFN1: M=4096, N=8192, K=2048 -> grid 32*16 = 512, GELU epilogue
  gemm256<2><<<dim3(512), blk, 0, stream>>>(
      a1b, wib, bi, nullptr, nullptr, hb, kM, kF, kD, kD);
  // FFN2: split-K x2 (grid 256), partials y2,f2p; LN2 fuses +bo2+attn_out(y1)
  gemm256<3><<<dim3(256), blk, 0, stream>>>(
      hb, wo2b, nullptr, y2, f2p, nullptr, kM, kD, kF, kF / 2);
  ln_fuse<false><<<kM, 256, 0, stream>>>(y2, f2p, bo2, y1, l2w, l2b, (float*)d_out, nullptr);
}

// Round 4
// 703.148 us; speedup vs baseline: 1.2868x; 1.0685x over previous
//
#include <hip/hip_runtime.h>
#include <hip/hip_bf16.h>
#include <cstdint>
#include <cstddef>

typedef __attribute__((ext_vector_type(8))) short short8;   // 8 x bf16 (4 VGPRs)
typedef __attribute__((ext_vector_type(4))) float f32x4;    // MFMA accumulator

#define DEV static __device__ __forceinline__

constexpr int kS = 1024, kD = 2048, kH = 16, kHD = 128, kF = 8192;
constexpr int kM = 4096;            // B*S rows
constexpr float kEPS = 1e-5f;

// ---------------- workspace layout (bytes) ----------------
constexpr size_t SZ_DD   = (size_t)kD * kD * 2;    // 8 MB   bf16 DxD weight
constexpr size_t SZ_FD   = (size_t)kF * kD * 2;    // 32 MB  bf16 FxD weight
constexpr size_t SZ_MD16 = (size_t)kM * kD * 2;    // 16 MB  bf16 activation
constexpr size_t SZ_MD32 = (size_t)kM * kD * 4;    // 32 MB  f32 activation
constexpr size_t OFF_WQ  = 0;                      // wq/wk/wv contiguous => fused QKV weight
constexpr size_t OFF_WK  = OFF_WQ + SZ_DD;
constexpr size_t OFF_WV  = OFF_WK + SZ_DD;
constexpr size_t OFF_WO  = OFF_WV + SZ_DD;
constexpr size_t OFF_WI  = OFF_WO + SZ_DD;
constexpr size_t OFF_WO2 = OFF_WI + SZ_FD;
constexpr size_t OFF_XB  = OFF_WO2 + SZ_FD;        // region reused for h later
constexpr size_t OFF_Q   = OFF_XB + SZ_MD16;       // q/k/vt contiguous (fused epilogue)
constexpr size_t OFF_K   = OFF_Q + SZ_MD16;
constexpr size_t OFF_V   = OFF_K + SZ_MD16;        // holds V^T layout [bh][hd][s]
constexpr size_t OFF_H   = OFF_XB;                 // 64 MB: xb+q+k+v dead by FFN1
constexpr size_t OFF_CTX = OFF_V + SZ_MD16;
constexpr size_t OFF_Y1  = OFF_CTX + SZ_MD16;      // f32
constexpr size_t OFF_A1B = OFF_Y1 + SZ_MD32;       // bf16 attn_out
constexpr size_t OFF_Y2  = OFF_A1B + SZ_MD16;      // f32 (first 24KB doubles as bqkv early)
constexpr size_t WS_NEED = OFF_Y2 + SZ_MD32;       // 256 MB total
// FFN2 second split-K partial reuses dead wq..wo region (4 x 8MB = 32MB) at OFF_WQ.

DEV void gload16(const void* g, void* l) {
  __builtin_amdgcn_global_load_lds(
      (const __attribute__((address_space(1))) unsigned int*)g,
      (__attribute__((address_space(3))) unsigned int*)l, 16, 0, 0);
}

// ---------------- fp32 -> bf16 convert ----------------
__global__ void cvt_bf16(const float* __restrict__ in, __hip_bfloat16* __restrict__ out, int n4) {
  int stride = gridDim.x * blockDim.x;
  for (int i = blockIdx.x * blockDim.x + threadIdx.x; i < n4; i += stride) {
    float4 v = reinterpret_cast<const float4*>(in)[i];
    union { ushort4 u; __hip_bfloat16 h[4]; } o;
    o.h[0] = __float2bfloat16(v.x);
    o.h[1] = __float2bfloat16(v.y);
    o.h[2] = __float2bfloat16(v.z);
    o.h[3] = __float2bfloat16(v.w);
    reinterpret_cast<ushort4*>(out)[i] = o.u;
  }
}

// ---------------- 256x256 4-phase/tile deep-pipelined GEMM, counted vmcnt ----------------
// C = A[MxK] * Bt[NxK]^T. BK=64, 8 waves arranged 2x4 INSIDE one 128x128
// C-quadrant; phases walk quadrants M0N0 -> M1N0 -> M1N1 -> M0N1 so half-tile
// consumption is progressive (P0: A0+B0, P1: +A1, P2: +B1, P3: A0 again).
// Staging of tile t+1 spread over tile t's phases (A0,B0,A1,B1); counted
// s_waitcnt vmcnt(4) validates only halves >=3 phases old — fresh loads are
// never drained (T4). 128 KiB LDS double-buffer.
// MODE 0: fused QKV scatter (q/k -> [b,h,s,hd], v -> [b,h,hd,s]), outb = q base
// MODE 2: out bf16 = gelu(acc + bias) at [row*N+col], outb
// MODE 3: raw f32 partial (split-K): out0/out1 selected by split index
template <int MODE>
__global__ __launch_bounds__(512, 2)
void gemm256(const __hip_bfloat16* __restrict__ A,
             const __hip_bfloat16* __restrict__ Bt,
             const float* __restrict__ bias,
             float* __restrict__ out0, float* __restrict__ out1,
             void* __restrict__ outb,
             int M, int N, int K, int kLen) {
  __shared__ __align__(16) char lds[131072];   // A: [2][256][64]b16 @0, B: @65536
  const int tid = threadIdx.x;
  const int lane = tid & 63, w = tid >> 6;
  const int wm = w >> 2, wn = w & 3;           // 2x4 waves inside a 128x128 quadrant
  const int lg = lane >> 4, lr = lane & 15;
  const int gy = M >> 8, gx = N >> 8;
  const int nwg = gridDim.x, orig = blockIdx.x;
  const int l = (orig & 7) * (nwg >> 3) + (orig >> 3);   // XCD-chunked (nwg%8==0)
  const int tilesPer = gx * gy;
  const int spl = l / tilesPer;
  const int rem = l - spl * tilesPer;
  const int bx = rem / gy, by = rem - bx * gy;           // n-panel-major
  const int m0 = by * 256, n0 = bx * 256;
  const int k0 = spl * kLen;
  const int NT = kLen >> 6;

  auto stageHalf = [&](int p, int half, int t) {
    // half: 0 = A rows 0-127, 1 = A rows 128-255, 2 = B rows 0-127, 3 = B rows 128-255
    const __hip_bfloat16* src = (half < 2) ? A : Bt;
    const int r0 = ((half < 2) ? m0 : n0) + (half & 1) * 128;
    char* dst = lds + ((half < 2) ? 0 : 65536) + p * 32768 + (half & 1) * 16384;
    const int kt = k0 + t * 64;
    #pragma unroll
    for (int i = 0; i < 2; ++i) {
      int c = i * 512 + tid;
      int row = c >> 3, slot = c & 7;
      gload16(src + (size_t)(r0 + row) * K + kt + (slot ^ (row & 7)) * 8, dst + c * 16);
    }
  };
  auto ldA = [&](int p, int qm, int mr, int kk) {
    int row = qm * 128 + wm * 64 + mr * 16 + lr;
    return *reinterpret_cast<const short8*>(
        lds + p * 32768 + row * 128 + (((kk * 4 + lg) ^ (row & 7)) * 16));
  };
  auto ldB = [&](int p, int qn, int nr, int kk) {
    int row = qn * 128 + wn * 32 + nr * 16 + lr;
    return *reinterpret_cast<const short8*>(
        lds + 65536 + p * 32768 + row * 128 + (((kk * 4 + lg) ^ (row & 7)) * 16));
  };

  f32x4 acc[4][4][2] = {};   // [quadrant][mr][nr]

#define MFMA_QUAD(q)                                                            \
  __builtin_amdgcn_s_setprio(1);                                               \
  _Pragma("unroll")                                                             \
  for (int kk = 0; kk < 2; ++kk)                                                \
    _Pragma("unroll")                                                           \
    for (int mi = 0; mi < 4; ++mi)                                              \
      _Pragma("unroll")                                                         \
      for (int ni = 0; ni < 2; ++ni)                                            \
        acc[q][mi][ni] = __builtin_amdgcn_mfma_f32_16x16x32_bf16(               \
            av[kk][mi], bv[kk][ni], acc[q][mi][ni], 0, 0, 0);                   \
  __builtin_amdgcn_s_setprio(0);

  // prologue: stage tile 0's halves in consumption order A0,B0,A1,B1
  stageHalf(0, 0, 0); stageHalf(0, 2, 0); stageHalf(0, 1, 0); stageHalf(0, 3, 0);
  asm volatile("s_waitcnt vmcnt(4)" ::: "memory");   // A0,B0 ready; A1,B1 in flight
  __builtin_amdgcn_s_barrier();

  for (int t = 0; t < NT; ++t) {
    const int p = t & 1;
    const bool pf = (t + 1 < NT);
    short8 av[2][4], bv[2][2];

    // ---- P0: quad 0 (M0,N0) — read A0,B0; stage A0(t+1)
    #pragma unroll
    for (int i = 0; i < 4; ++i) { av[0][i] = ldA(p, 0, i, 0); av[1][i] = ldA(p, 0, i, 1); }
    #pragma unroll
    for (int i = 0; i < 2; ++i) { bv[0][i] = ldB(p, 0, i, 0); bv[1][i] = ldB(p, 0, i, 1); }
    if (pf) stageHalf(p ^ 1, 0, t + 1);
    __builtin_amdgcn_s_barrier();
    asm volatile("s_waitcnt lgkmcnt(0)" ::: "memory");
    __builtin_amdgcn_sched_barrier(0);
    MFMA_QUAD(0)
    if (pf) { asm volatile("s_waitcnt vmcnt(4)" ::: "memory"); }   // A1(t) ready
    else    { asm volatile("s_waitcnt vmcnt(2)" ::: "memory"); }
    __builtin_amdgcn_s_barrier();

    // ---- P1: quad 1 (M1,N0) — read A1, reuse bv; stage B0(t+1)
    #pragma unroll
    for (int i = 0; i < 4; ++i) { av[0][i] = ldA(p, 1, i, 0); av[1][i] = ldA(p, 1, i, 1); }
    if (pf) stageHalf(p ^ 1, 2, t + 1);
    __builtin_amdgcn_s_barrier();
    asm volatile("s_waitcnt lgkmcnt(0)" ::: "memory");
    __builtin_amdgcn_sched_barrier(0);
    MFMA_QUAD(1)
    if (pf) { asm volatile("s_waitcnt vmcnt(4)" ::: "memory"); }   // B1(t) ready
    else    { asm volatile("s_waitcnt vmcnt(0)" ::: "memory"); }
    __builtin_amdgcn_s_barrier();

    // ---- P2: quad 2 (M1,N1) — read B1, reuse av; stage A1(t+1)
    #pragma unroll
    for (int i = 0; i < 2; ++i) { bv[0][i] = ldB(p, 1, i, 0); bv[1][i] = ldB(p, 1, i, 1); }
    if (pf) stageHalf(p ^ 1, 1, t + 1);
    __builtin_amdgcn_s_barrier();
    asm volatile("s_waitcnt lgkmcnt(0)" ::: "memory");
    __builtin_amdgcn_sched_barrier(0);
    MFMA_QUAD(2)
    __builtin_amdgcn_s_barrier();

    // ---- P3: quad 3 (M0,N1) — re-read A0, reuse bv; stage B1(t+1)
    #pragma unroll
    for (int i = 0; i < 4; ++i) { av[0][i] = ldA(p, 0, i, 0); av[1][i] = ldA(p, 0, i, 1); }
    if (pf) stageHalf(p ^ 1, 3, t + 1);
    __builtin_amdgcn_s_barrier();
    asm volatile("s_waitcnt lgkmcnt(0)" ::: "memory");
    __builtin_amdgcn_sched_barrier(0);
    MFMA_QUAD(3)
    if (pf) { asm volatile("s_waitcnt vmcnt(4)" ::: "memory"); }   // A0,B0(t+1) ready
    __builtin_amdgcn_s_barrier();
  }
#undef MFMA_QUAD

  // epilogue: row = m0+qm*128+wm*64+mr*16+lg*4+r, col = n0+qn*128+wn*32+nr*16+lr
  #pragma unroll
  for (int q = 0; q < 4; ++q) {
    const int qm = (q == 1 || q == 2) ? 1 : 0;
    const int qn = (q >= 2) ? 1 : 0;
    #pragma unroll
    for (int ni = 0; ni < 2; ++ni) {
      int col = n0 + qn * 128 + wn * 32 + ni * 16 + lr;
      float bvv = 0.f;
      if constexpr (MODE != 3) bvv = bias[col];
      #pragma unroll
      for (int mi = 0; mi < 4; ++mi) {
        int row0 = m0 + qm * 128 + wm * 64 + mi * 16 + lg * 4;
        #pragma unroll
        for (int r = 0; r < 4; ++r) {
          int row = row0 + r;
          float val = acc[q][mi][ni][r] + bvv;
          if constexpr (MODE == 0) {
            int which = col >> 11;                  // 0=q 1=k 2=v
            int d = col & 2047;
            int hh = d >> 7, hd = d & 127;
            int bb = row >> 10, ss = row & 1023;
            __hip_bfloat16* base = (__hip_bfloat16*)outb + (size_t)which * ((size_t)kM * kD);
            if (which < 2)
              base[(((size_t)(bb * kH + hh)) * kS + ss) * kHD + hd] = __float2bfloat16(val);
            else
              base[(((size_t)(bb * kH + hh)) * kHD + hd) * kS + ss] = __float2bfloat16(val);
          } else if constexpr (MODE == 2) {
            float g = 0.5f * val * (1.0f + erff(val * 0.70710678118654752f));
            ((__hip_bfloat16*)outb)[(size_t)row * N + col] = __float2bfloat16(g);
          } else {
            float* o = spl ? out1 : out0;
            o[(size_t)row * N + col] = val;
          }
        }
      }
    }
  }
}

// ---------------- flash attention (unchanged) ----------------
__global__ __launch_bounds__(512, 4)
void attn_fwd(const __hip_bfloat16* __restrict__ q,
              const __hip_bfloat16* __restrict__ k,
              const __hip_bfloat16* __restrict__ vt,
              const float* __restrict__ mask,
              __hip_bfloat16* __restrict__ ctx) {
  __shared__ __align__(16) char Ks[2][64 * 256];    // [buf][key][dim] slot16^(row&15)
  __shared__ __align__(16) char Vt[2][128 * 128];   // [buf][hd][key64] slot8^(row&7)
  __shared__ __align__(16) char Ps[8][2048];        // per-wave P [16][64], ^((row&7)<<4)
  const int tid = threadIdx.x, lane = tid & 63, w = tid >> 6;
  const int lg = lane >> 4, lr = lane & 15;
  const int orig = blockIdx.x;                      // 512 blocks
  const int l = (orig & 7) * 64 + (orig >> 3);      // XCD-chunked: 8 bh per XCD
  const int qt = l & 7, bh = l >> 3;
  const int b = bh >> 4;

  short8 qf[4];
  {
    const __hip_bfloat16* qp =
        q + ((size_t)bh * kS + qt * 128 + w * 16 + lr) * kHD + lg * 8;
    #pragma unroll
    for (int kk = 0; kk < 4; ++kk) qf[kk] = *reinterpret_cast<const short8*>(qp + kk * 32);
  }

  auto stage = [&](int bufi, int t) {
    #pragma unroll
    for (int i = 0; i < 2; ++i) {                   // K tile: 64 rows x 256B
      int c = i * 512 + tid;
      int row = c >> 4, slot = c & 15;
      gload16(k + ((size_t)bh * kS + t * 64 + row) * kHD + (slot ^ (row & 15)) * 8,
              Ks[bufi] + c * 16);
    }
    #pragma unroll
    for (int i = 0; i < 2; ++i) {                   // V^T tile: 128 rows x 128B
      int c = i * 512 + tid;
      int row = c >> 3, slot = c & 7;
      gload16(vt + ((size_t)bh * kHD + row) * kS + t * 64 + (slot ^ (row & 7)) * 8,
              Vt[bufi] + c * 16);
    }
  };

  f32x4 o[8] = {};
  float mrun[4], lrun[4];
  #pragma unroll
  for (int r = 0; r < 4; ++r) { mrun[r] = -1e30f; lrun[r] = 0.f; }
  const float scale = 0.08838834764831845f;         // 1/sqrt(128)

  stage(0, 0);
  __syncthreads();

  int buf = 0;
  for (int t = 0; t < 16; ++t) {
    if (t + 1 < 16) stage(buf ^ 1, t + 1);

    f32x4 sacc[4] = {};
    #pragma unroll
    for (int j = 0; j < 4; ++j) {
      int key = j * 16 + lr;
      #pragma unroll
      for (int kk = 0; kk < 4; ++kk) {
        short8 bfrag = *reinterpret_cast<const short8*>(
            Ks[buf] + key * 256 + (((kk * 4 + lg) ^ (key & 15)) * 16));
        sacc[j] = __builtin_amdgcn_mfma_f32_16x16x32_bf16(qf[kk], bfrag, sacc[j], 0, 0, 0);
      }
    }
    float sarr[4][4];
    #pragma unroll
    for (int j = 0; j < 4; ++j) {
      float mv = mask[(size_t)b * kS + t * 64 + j * 16 + lr];
      #pragma unroll
      for (int r = 0; r < 4; ++r) sarr[j][r] = sacc[j][r] * scale + mv;
    }
    #pragma unroll
    for (int r = 0; r < 4; ++r) {
      float tm = fmaxf(fmaxf(sarr[0][r], sarr[1][r]), fmaxf(sarr[2][r], sarr[3][r]));
      #pragma unroll
      for (int d = 1; d < 16; d <<= 1) tm = fmaxf(tm, __shfl_xor(tm, d));
      float mnew = fmaxf(mrun[r], tm);
      float alpha = __expf(mrun[r] - mnew);
      mrun[r] = mnew;
      float rs = 0.f;
      #pragma unroll
      for (int j = 0; j < 4; ++j) {
        float p = __expf(sarr[j][r] - mnew);
        sarr[j][r] = p;
        rs += p;
      }
      #pragma unroll
      for (int d = 1; d < 16; d <<= 1) rs += __shfl_xor(rs, d);
      lrun[r] = lrun[r] * alpha + rs;
      #pragma unroll
      for (int n = 0; n < 8; ++n) o[n][r] *= alpha;
    }
    #pragma unroll
    for (int r = 0; r < 4; ++r) {
      int qr = lg * 4 + r;
      #pragma unroll
      for (int j = 0; j < 4; ++j)
        *reinterpret_cast<__hip_bfloat16*>(
            Ps[w] + ((qr * 128 + (j * 16 + lr) * 2) ^ ((qr & 7) << 4))) =
            __float2bfloat16(sarr[j][r]);
    }
    #pragma unroll
    for (int kk2 = 0; kk2 < 2; ++kk2) {
      short8 pa = *reinterpret_cast<const short8*>(
          Ps[w] + ((lr * 128 + kk2 * 64 + lg * 16) ^ ((lr & 7) << 4)));
      #pragma unroll
      for (int n = 0; n < 8; ++n) {
        int hd = n * 16 + lr;
        short8 vb = *reinterpret_cast<const short8*>(
            Vt[buf] + hd * 128 + (((kk2 * 4 + lg) ^ (hd & 7)) * 16));
        o[n] = __builtin_amdgcn_mfma_f32_16x16x32_bf16(pa, vb, o[n], 0, 0, 0);
      }
    }
    __syncthreads();
    buf ^= 1;
  }

  const int h = bh & 15;
  #pragma unroll
  for (int r = 0; r < 4; ++r) {
    float inv = 1.0f / lrun[r];
    int srow = qt * 128 + w * 16 + lg * 4 + r;
    __hip_bfloat16* cp = ctx + ((size_t)b * kS + srow) * kD + h * 128 + lr;
    #pragma unroll
    for (int n = 0; n < 8; ++n) cp[n * 16] = __float2bfloat16(o[n][r] * inv);
  }
}

// ------- LayerNorm over (p0 + p1 + bias + res), one 2048-row per block -------
template <bool WB16>
__global__ void ln_fuse(const float* __restrict__ p0, const float* __restrict__ p1,
                        const float* __restrict__ bias, const float* __restrict__ res,
                        const float* __restrict__ w, const float* __restrict__ b,
                        float* __restrict__ outf, __hip_bfloat16* __restrict__ outb) {
  const int row = blockIdx.x, tid = threadIdx.x;
  const size_t base = (size_t)row * kD;
  float v[8];
  #pragma unroll
  for (int i = 0; i < 2; ++i) {
    int c4 = tid * 2 + i;
    float4 a  = reinterpret_cast<const float4*>(p0 + base)[c4];
    float4 bb = reinterpret_cast<const float4*>(p1 + base)[c4];
    float4 rr = reinterpret_cast<const float4*>(res + base)[c4];
    float4 bs = reinterpret_cast<const float4*>(bias)[c4];
    v[i * 4 + 0] = a.x + bb.x + rr.x + bs.x;
    v[i * 4 + 1] = a.y + bb.y + rr.y + bs.y;
    v[i * 4 + 2] = a.z + bb.z + rr.z + bs.z;
    v[i * 4 + 3] = a.w + bb.w + rr.w + bs.w;
  }
  float s = 0.f;
  #pragma unroll
  for (int i = 0; i < 8; ++i) s += v[i];
  #pragma unroll
  for (int off = 32; off > 0; off >>= 1) s += __shfl_down(s, off);
  __shared__ float r1[4], r2[4];
  if ((tid & 63) == 0) r1[tid >> 6] = s;
  __syncthreads();
  float mean = (r1[0] + r1[1] + r1[2] + r1[3]) * (1.0f / kD);
  float qv = 0.f;
  #pragma unroll
  for (int i = 0; i < 8; ++i) { float d = v[i] - mean; qv += d * d; }
  #pragma unroll
  for (int off = 32; off > 0; off >>= 1) qv += __shfl_down(qv, off);
  if ((tid & 63) == 0) r2[tid >> 6] = qv;
  __syncthreads();
  float rstd = rsqrtf((r2[0] + r2[1] + r2[2] + r2[3]) * (1.0f / kD) + kEPS);
  #pragma unroll
  for (int i = 0; i < 8; ++i) {
    int col = tid * 8 + i;
    float ov = (v[i] - mean) * rstd * w[col] + b[col];
    outf[base + col] = ov;
    if constexpr (WB16) outb[base + col] = __float2bfloat16(ov);
  }
}

// ---------------- launcher ----------------
extern "C" void kernel_launch(void* const* d_in, const int* in_sizes, int n_in,
                              void* d_out, int out_size, void* d_ws, size_t ws_size,
                              hipStream_t stream) {
  (void)in_sizes; (void)n_in; (void)out_size;
  if (ws_size < WS_NEED) return;
  const float* x    = (const float*)d_in[0];
  const float* mask = (const float*)d_in[1];
  const float* wq   = (const float*)d_in[2];
  const float* bq   = (const float*)d_in[3];
  const float* wk   = (const float*)d_in[4];
  const float* bk   = (const float*)d_in[5];
  const float* wv   = (const float*)d_in[6];
  const float* bv   = (const float*)d_in[7];
  const float* wo   = (const float*)d_in[8];
  const float* bo   = (const float*)d_in[9];
  const float* l1w  = (const float*)d_in[10];
  const float* l1b  = (const float*)d_in[11];
  const float* wi   = (const float*)d_in[12];
  const float* bi   = (const float*)d_in[13];
  const float* wo2  = (const float*)d_in[14];
  const float* bo2  = (const float*)d_in[15];
  const float* l2w  = (const float*)d_in[16];
  const float* l2b  = (const float*)d_in[17];

  char* ws = (char*)d_ws;
  __hip_bfloat16* wqb  = (__hip_bfloat16*)(ws + OFF_WQ);   // fused QKV weight base
  __hip_bfloat16* wkb  = (__hip_bfloat16*)(ws + OFF_WK);
  __hip_bfloat16* wvb  = (__hip_bfloat16*)(ws + OFF_WV);
  __hip_bfloat16* wob  = (__hip_bfloat16*)(ws + OFF_WO);
  __hip_bfloat16* wib  = (__hip_bfloat16*)(ws + OFF_WI);
  __hip_bfloat16* wo2b = (__hip_bfloat16*)(ws + OFF_WO2);
  __hip_bfloat16* xb   = (__hip_bfloat16*)(ws + OFF_XB);
  __hip_bfloat16* qb   = (__hip_bfloat16*)(ws + OFF_Q);    // q/k/vt contiguous
  __hip_bfloat16* kb2  = (__hip_bfloat16*)(ws + OFF_K);
  __hip_bfloat16* vtb  = (__hip_bfloat16*)(ws + OFF_V);
  __hip_bfloat16* hb   = (__hip_bfloat16*)(ws + OFF_H);
  __hip_bfloat16* ctxb = (__hip_bfloat16*)(ws + OFF_CTX);
  __hip_bfloat16* a1b  = (__hip_bfloat16*)(ws + OFF_A1B);
  float* y1   = (float*)(ws + OFF_Y1);
  float* y2   = (float*)(ws + OFF_Y2);
  float* f2p  = (float*)(ws + OFF_WQ);   // FFN2 split-K partial 1 (32MB, weights dead)
  float* bqkv = (float*)(ws + OFF_Y2);   // 24KB concat bias; dead before Wo writes y2

  // fp32 -> bf16 conversions
  cvt_bf16<<<2048, 256, 0, stream>>>(x,   xb,   kM * kD / 4);
  cvt_bf16<<<1024, 256, 0, stream>>>(wq,  wqb,  kD * kD / 4);
  cvt_bf16<<<1024, 256, 0, stream>>>(wk,  wkb,  kD * kD / 4);
  cvt_bf16<<<1024, 256, 0, stream>>>(wv,  wvb,  kD * kD / 4);
  cvt_bf16<<<1024, 256, 0, stream>>>(wo,  wob,  kD * kD / 4);
  cvt_bf16<<<2048, 256, 0, stream>>>(wi,  wib,  kF * kD / 4);
  cvt_bf16<<<2048, 256, 0, stream>>>(wo2, wo2b, kF * kD / 4);
  // concat QKV bias into scratch
  hipMemcpyAsync(bqkv,          bq, kD * 4, hipMemcpyDeviceToDevice, stream);
  hipMemcpyAsync(bqkv + kD,     bk, kD * 4, hipMemcpyDeviceToDevice, stream);
  hipMemcpyAsync(bqkv + 2 * kD, bv, kD * 4, hipMemcpyDeviceToDevice, stream);

  dim3 blk(512);
  // fused QKV projection: M=4096, N=6144, K=2048 -> grid 24*16 = 384
  gemm256<0><<<dim3(384), blk, 0, stream>>>(
      xb, wqb, bqkv, nullptr, nullptr, qb, kM, 6144, kD, kD);
  // attention
  attn_fwd<<<dim3(512), dim3(512), 0, stream>>>(qb, kb2, vtb, mask, ctxb);
  // out proj, split-K x2 (grid 2*8*16 = 256), partials y1,y2; LN1 fuses +bo+x
  gemm256<3><<<dim3(256), blk, 0, stream>>>(
      ctxb, wob, nullptr, y1, y2, nullptr, kM, kD, kD, kD / 2);
  ln_fuse<true><<<kM, 256, 0, stream>>>(y1, y2, bo, x, l1w, l1b, y1, a1b);
  // FFN1: M=4096, N=8192, K=2048 -> grid 32*16 = 512, GELU epilogue
  gemm256<2><<<dim3(512), blk, 0, stream>>>(
      a1b, wib, bi, nullptr, nullptr, hb, kM, kF, kD, kD);
  // FFN2: split-K x2 (grid 256), partials y2,f2p; LN2 fuses +bo2+attn_out(y1)
  gemm256<3><<<dim3(256), blk, 0, stream>>>(
      hb, wo2b, nullptr, y2, f2p, nullptr, kM, kD, kF, kF / 2);
  ln_fuse<false><<<kM, 256, 0, stream>>>(y2, f2p, bo2, y1, l2w, l2b, (float*)d_out, nullptr);
}

// Round 5
// 688.928 us; speedup vs baseline: 1.3134x; 1.0206x over previous
//
#include <hip/hip_runtime.h>
#include <hip/hip_bf16.h>
#include <cstdint>
#include <cstddef>

typedef __attribute__((ext_vector_type(8))) short short8;   // 8 x bf16 (4 VGPRs)
typedef __attribute__((ext_vector_type(4))) float f32x4;    // MFMA accumulator

#define DEV static __device__ __forceinline__

constexpr int kS = 1024, kD = 2048, kH = 16, kHD = 128, kF = 8192;
constexpr int kM = 4096;            // B*S rows
constexpr float kEPS = 1e-5f;

// ---------------- workspace layout (bytes) ----------------
constexpr size_t SZ_DD   = (size_t)kD * kD * 2;    // 8 MB   bf16 DxD weight
constexpr size_t SZ_FD   = (size_t)kF * kD * 2;    // 32 MB  bf16 FxD weight
constexpr size_t SZ_MD16 = (size_t)kM * kD * 2;    // 16 MB  bf16 activation
constexpr size_t SZ_MD32 = (size_t)kM * kD * 4;    // 32 MB  f32 activation
constexpr size_t OFF_WQ  = 0;                      // wq/wk/wv contiguous => fused QKV weight
constexpr size_t OFF_WK  = OFF_WQ + SZ_DD;
constexpr size_t OFF_WV  = OFF_WK + SZ_DD;
constexpr size_t OFF_WO  = OFF_WV + SZ_DD;
constexpr size_t OFF_WI  = OFF_WO + SZ_DD;
constexpr size_t OFF_WO2 = OFF_WI + SZ_FD;
constexpr size_t OFF_XB  = OFF_WO2 + SZ_FD;        // region reused for h later
constexpr size_t OFF_Q   = OFF_XB + SZ_MD16;       // q/k/vt contiguous (fused epilogue)
constexpr size_t OFF_K   = OFF_Q + SZ_MD16;
constexpr size_t OFF_V   = OFF_K + SZ_MD16;        // holds V^T layout [bh][hd][s]
constexpr size_t OFF_H   = OFF_XB;                 // 64 MB: xb+q+k+v dead by FFN1
constexpr size_t OFF_CTX = OFF_V + SZ_MD16;
constexpr size_t OFF_Y1  = OFF_CTX + SZ_MD16;      // f32
constexpr size_t OFF_A1B = OFF_Y1 + SZ_MD32;       // bf16 attn_out
constexpr size_t OFF_Y2  = OFF_A1B + SZ_MD16;      // f32 (first 24KB doubles as bqkv early)
constexpr size_t WS_NEED = OFF_Y2 + SZ_MD32;       // 256 MB total
// FFN2 second split-K partial reuses dead wq..wo region (4 x 8MB = 32MB) at OFF_WQ.

DEV void gload16(const void* g, void* l) {
  __builtin_amdgcn_global_load_lds(
      (const __attribute__((address_space(1))) unsigned int*)g,
      (__attribute__((address_space(3))) unsigned int*)l, 16, 0, 0);
}

// ---------------- fp32 -> bf16 convert ----------------
__global__ void cvt_bf16(const float* __restrict__ in, __hip_bfloat16* __restrict__ out, int n4) {
  int stride = gridDim.x * blockDim.x;
  for (int i = blockIdx.x * blockDim.x + threadIdx.x; i < n4; i += stride) {
    float4 v = reinterpret_cast<const float4*>(in)[i];
    union { ushort4 u; __hip_bfloat16 h[4]; } o;
    o.h[0] = __float2bfloat16(v.x);
    o.h[1] = __float2bfloat16(v.y);
    o.h[2] = __float2bfloat16(v.z);
    o.h[3] = __float2bfloat16(v.w);
    reinterpret_cast<ushort4*>(out)[i] = o.u;
  }
}

// ---------------- 256x256 deep-pipelined GEMM, 2 K-tiles/iter ----------------
// C = A[MxK] * Bt[NxK]^T. BK=64, 8 waves 2x4 inside one 128x128 C-quadrant;
// phases walk quadrants M0N0 -> M1N0 -> M1N1 -> M0N1 (progressive half-tile
// consumption). Tile t+1's halves staged across tile t's phases (A0,B0,A1,B1);
// counted s_waitcnt vmcnt(4): only halves >=2 phases old are drained (T4).
// K-loop unrolled x2 so buffer parity P is a literal: LDS addrs loop-invariant
// (p*32768 folds to ds offset field), staging ptrs advance by += 256 B/iter.
// MODE 0: fused QKV scatter (q/k -> [b,h,s,hd], v -> [b,h,hd,s]), outb = q base
// MODE 2: out bf16 = gelu(acc + bias) at [row*N+col], outb
// MODE 3: raw f32 partial (split-K): out0/out1 selected by split index
template <int MODE>
__global__ __launch_bounds__(512, 2)
void gemm256(const __hip_bfloat16* __restrict__ A,
             const __hip_bfloat16* __restrict__ Bt,
             const float* __restrict__ bias,
             float* __restrict__ out0, float* __restrict__ out1,
             void* __restrict__ outb,
             int M, int N, int K, int kLen) {
  __shared__ __align__(16) char lds[131072];   // A: [2][256][64]b16 @0, B: @65536
  const int tid = threadIdx.x;
  const int lane = tid & 63, w = tid >> 6;
  const int wm = w >> 2, wn = w & 3;           // 2x4 waves inside a 128x128 quadrant
  const int lg = lane >> 4, lr = lane & 15;
  const int gy = M >> 8, gx = N >> 8;
  const int nwg = gridDim.x, orig = blockIdx.x;
  const int l = (orig & 7) * (nwg >> 3) + (orig >> 3);   // XCD-chunked (nwg%8==0)
  const int tilesPer = gx * gy;
  const int spl = l / tilesPer;
  const int rem = l - spl * tilesPer;
  const int bx = rem / gy, by = rem - bx * gy;           // n-panel-major
  const int m0 = by * 256, n0 = bx * 256;
  const int k0 = spl * kLen;
  const int NT = kLen >> 6;                               // even for all our shapes

  // staging source pointers (half 0=A0,1=A1,2=B0,3=B1; i 0..1), tile-0 based
  const char* gs[8];
  #pragma unroll
  for (int h = 0; h < 4; ++h) {
    const __hip_bfloat16* src = (h < 2) ? A : Bt;
    const int r0 = ((h < 2) ? m0 : n0) + (h & 1) * 128;
    #pragma unroll
    for (int i = 0; i < 2; ++i) {
      int c = i * 512 + tid;
      int row = c >> 3, slot = c & 7;
      gs[h * 2 + i] =
          (const char*)(src + (size_t)(r0 + row) * K + k0 + (slot ^ (row & 7)) * 8);
    }
  }

#define STAGE(P, H, TOFF)                                                          \
  {                                                                                \
    char* dstb = lds + (((H) < 2) ? 0 : 65536) + (P) * 32768 + ((H) & 1) * 16384;  \
    gload16(gs[(H) * 2 + 0] + (TOFF) * 128, dstb + (0 * 512 + tid) * 16);          \
    gload16(gs[(H) * 2 + 1] + (TOFF) * 128, dstb + (1 * 512 + tid) * 16);          \
  }

  auto ldA = [&](int P, int qm, int mr, int kk) {
    int row = qm * 128 + wm * 64 + mr * 16 + lr;
    return *reinterpret_cast<const short8*>(
        lds + P * 32768 + row * 128 + (((kk * 4 + lg) ^ (row & 7)) * 16));
  };
  auto ldB = [&](int P, int qn, int nr, int kk) {
    int row = qn * 128 + wn * 32 + nr * 16 + lr;
    return *reinterpret_cast<const short8*>(
        lds + 65536 + P * 32768 + row * 128 + (((kk * 4 + lg) ^ (row & 7)) * 16));
  };

  f32x4 acc[4][4][2] = {};   // [quadrant][mr][nr]

#define MFMA_QUAD(q)                                                            \
  __builtin_amdgcn_s_setprio(1);                                                \
  _Pragma("unroll")                                                             \
  for (int kk = 0; kk < 2; ++kk)                                                \
    _Pragma("unroll")                                                           \
    for (int mi = 0; mi < 4; ++mi)                                              \
      _Pragma("unroll")                                                         \
      for (int ni = 0; ni < 2; ++ni)                                            \
        acc[q][mi][ni] = __builtin_amdgcn_mfma_f32_16x16x32_bf16(               \
            av[kk][mi], bv[kk][ni], acc[q][mi][ni], 0, 0, 0);                   \
  __builtin_amdgcn_s_setprio(0);

// One K-tile body; P = literal buffer parity, PF = prefetch next tile,
// TOFF = (next tile) - (gs base tile) = 1 + P.
#define TILE_BODY(P, PF)                                                        \
  {                                                                             \
    /* P0: quad 0 (M0,N0) — read A0,B0; stage A0(next) */                       \
    _Pragma("unroll")                                                           \
    for (int i = 0; i < 4; ++i) { av[0][i] = ldA(P, 0, i, 0); av[1][i] = ldA(P, 0, i, 1); } \
    _Pragma("unroll")                                                           \
    for (int i = 0; i < 2; ++i) { bv[0][i] = ldB(P, 0, i, 0); bv[1][i] = ldB(P, 0, i, 1); } \
    if (PF) STAGE((P) ^ 1, 0, 1 + (P));                                         \
    __builtin_amdgcn_s_barrier();                                               \
    asm volatile("s_waitcnt lgkmcnt(0)" ::: "memory");                          \
    __builtin_amdgcn_sched_barrier(0);                                          \
    MFMA_QUAD(0)                                                                \
    if (PF) { asm volatile("s_waitcnt vmcnt(4)" ::: "memory"); }                \
    else    { asm volatile("s_waitcnt vmcnt(2)" ::: "memory"); }                \
    __builtin_amdgcn_s_barrier();                                               \
    /* P1: quad 1 (M1,N0) — read A1, reuse bv; stage B0(next) */                \
    _Pragma("unroll")                                                           \
    for (int i = 0; i < 4; ++i) { av[0][i] = ldA(P, 1, i, 0); av[1][i] = ldA(P, 1, i, 1); } \
    if (PF) STAGE((P) ^ 1, 2, 1 + (P));                                         \
    __builtin_amdgcn_s_barrier();                                               \
    asm volatile("s_waitcnt lgkmcnt(0)" ::: "memory");                          \
    __builtin_amdgcn_sched_barrier(0);                                          \
    MFMA_QUAD(1)                                                                \
    if (PF) { asm volatile("s_waitcnt vmcnt(4)" ::: "memory"); }                \
    else    { asm volatile("s_waitcnt vmcnt(0)" ::: "memory"); }                \
    __builtin_amdgcn_s_barrier();                                               \
    /* P2: quad 2 (M1,N1) — read B1, reuse av; stage A1(next) */                \
    _Pragma("unroll")                                                           \
    for (int i = 0; i < 2; ++i) { bv[0][i] = ldB(P, 1, i, 0); bv[1][i] = ldB(P, 1, i, 1); } \
    if (PF) STAGE((P) ^ 1, 1, 1 + (P));                                         \
    __builtin_amdgcn_s_barrier();                                               \
    asm volatile("s_waitcnt lgkmcnt(0)" ::: "memory");                          \
    __builtin_amdgcn_sched_barrier(0);                                          \
    MFMA_QUAD(2)                                                                \
    __builtin_amdgcn_s_barrier();                                               \
    /* P3: quad 3 (M0,N1) — re-read A0, reuse bv; stage B1(next) */             \
    _Pragma("unroll")                                                           \
    for (int i = 0; i < 4; ++i) { av[0][i] = ldA(P, 0, i, 0); av[1][i] = ldA(P, 0, i, 1); } \
    if (PF) STAGE((P) ^ 1, 3, 1 + (P));                                         \
    __builtin_amdgcn_s_barrier();                                               \
    asm volatile("s_waitcnt lgkmcnt(0)" ::: "memory");                          \
    __builtin_amdgcn_sched_barrier(0);                                          \
    MFMA_QUAD(3)                                                                \
    if (PF) { asm volatile("s_waitcnt vmcnt(4)" ::: "memory"); }                \
    __builtin_amdgcn_s_barrier();                                               \
  }

  // prologue: stage tile 0's halves in consumption order A0,B0,A1,B1
  STAGE(0, 0, 0) STAGE(0, 2, 0) STAGE(0, 1, 0) STAGE(0, 3, 0)
  asm volatile("s_waitcnt vmcnt(4)" ::: "memory");   // A0,B0 ready; A1,B1 in flight
  __builtin_amdgcn_s_barrier();

  for (int t2 = 0; t2 < NT; t2 += 2) {
    short8 av[2][4], bv[2][2];
    TILE_BODY(0, true)
    TILE_BODY(1, (t2 + 2 < NT))
    #pragma unroll
    for (int j = 0; j < 8; ++j) gs[j] += 256;
  }
#undef TILE_BODY
#undef MFMA_QUAD
#undef STAGE

  // epilogue: row = m0+qm*128+wm*64+mi*16+lg*4+r, col = n0+qn*128+wn*32+ni*16+lr
  #pragma unroll
  for (int q = 0; q < 4; ++q) {
    const int qm = (q == 1 || q == 2) ? 1 : 0;
    const int qn = (q >= 2) ? 1 : 0;
    #pragma unroll
    for (int ni = 0; ni < 2; ++ni) {
      int col = n0 + qn * 128 + wn * 32 + ni * 16 + lr;
      float bvv = 0.f;
      if constexpr (MODE != 3) bvv = bias[col];
      #pragma unroll
      for (int mi = 0; mi < 4; ++mi) {
        int row0 = m0 + qm * 128 + wm * 64 + mi * 16 + lg * 4;
        #pragma unroll
        for (int r = 0; r < 4; ++r) {
          int row = row0 + r;
          float val = acc[q][mi][ni][r] + bvv;
          if constexpr (MODE == 0) {
            int which = col >> 11;                  // 0=q 1=k 2=v
            int d = col & 2047;
            int hh = d >> 7, hd = d & 127;
            int bb = row >> 10, ss = row & 1023;
            __hip_bfloat16* base = (__hip_bfloat16*)outb + (size_t)which * ((size_t)kM * kD);
            if (which < 2)
              base[(((size_t)(bb * kH + hh)) * kS + ss) * kHD + hd] = __float2bfloat16(val);
            else
              base[(((size_t)(bb * kH + hh)) * kHD + hd) * kS + ss] = __float2bfloat16(val);
          } else if constexpr (MODE == 2) {
            float g = 0.5f * val * (1.0f + erff(val * 0.70710678118654752f));
            ((__hip_bfloat16*)outb)[(size_t)row * N + col] = __float2bfloat16(g);
          } else {
            float* o = spl ? out1 : out0;
            o[(size_t)row * N + col] = val;
          }
        }
      }
    }
  }
}

// ---------------- flash attention (unchanged) ----------------
__global__ __launch_bounds__(512, 4)
void attn_fwd(const __hip_bfloat16* __restrict__ q,
              const __hip_bfloat16* __restrict__ k,
              const __hip_bfloat16* __restrict__ vt,
              const float* __restrict__ mask,
              __hip_bfloat16* __restrict__ ctx) {
  __shared__ __align__(16) char Ks[2][64 * 256];    // [buf][key][dim] slot16^(row&15)
  __shared__ __align__(16) char Vt[2][128 * 128];   // [buf][hd][key64] slot8^(row&7)
  __shared__ __align__(16) char Ps[8][2048];        // per-wave P [16][64], ^((row&7)<<4)
  const int tid = threadIdx.x, lane = tid & 63, w = tid >> 6;
  const int lg = lane >> 4, lr = lane & 15;
  const int orig = blockIdx.x;                      // 512 blocks
  const int l = (orig & 7) * 64 + (orig >> 3);      // XCD-chunked: 8 bh per XCD
  const int qt = l & 7, bh = l >> 3;
  const int b = bh >> 4;

  short8 qf[4];
  {
    const __hip_bfloat16* qp =
        q + ((size_t)bh * kS + qt * 128 + w * 16 + lr) * kHD + lg * 8;
    #pragma unroll
    for (int kk = 0; kk < 4; ++kk) qf[kk] = *reinterpret_cast<const short8*>(qp + kk * 32);
  }

  auto stage = [&](int bufi, int t) {
    #pragma unroll
    for (int i = 0; i < 2; ++i) {                   // K tile: 64 rows x 256B
      int c = i * 512 + tid;
      int row = c >> 4, slot = c & 15;
      gload16(k + ((size_t)bh * kS + t * 64 + row) * kHD + (slot ^ (row & 15)) * 8,
              Ks[bufi] + c * 16);
    }
    #pragma unroll
    for (int i = 0; i < 2; ++i) {                   // V^T tile: 128 rows x 128B
      int c = i * 512 + tid;
      int row = c >> 3, slot = c & 7;
      gload16(vt + ((size_t)bh * kHD + row) * kS + t * 64 + (slot ^ (row & 7)) * 8,
              Vt[bufi] + c * 16);
    }
  };

  f32x4 o[8] = {};
  float mrun[4], lrun[4];
  #pragma unroll
  for (int r = 0; r < 4; ++r) { mrun[r] = -1e30f; lrun[r] = 0.f; }
  const float scale = 0.08838834764831845f;         // 1/sqrt(128)

  stage(0, 0);
  __syncthreads();

  int buf = 0;
  for (int t = 0; t < 16; ++t) {
    if (t + 1 < 16) stage(buf ^ 1, t + 1);

    f32x4 sacc[4] = {};
    #pragma unroll
    for (int j = 0; j < 4; ++j) {
      int key = j * 16 + lr;
      #pragma unroll
      for (int kk = 0; kk < 4; ++kk) {
        short8 bfrag = *reinterpret_cast<const short8*>(
            Ks[buf] + key * 256 + (((kk * 4 + lg) ^ (key & 15)) * 16));
        sacc[j] = __builtin_amdgcn_mfma_f32_16x16x32_bf16(qf[kk], bfrag, sacc[j], 0, 0, 0);
      }
    }
    float sarr[4][4];
    #pragma unroll
    for (int j = 0; j < 4; ++j) {
      float mv = mask[(size_t)b * kS + t * 64 + j * 16 + lr];
      #pragma unroll
      for (int r = 0; r < 4; ++r) sarr[j][r] = sacc[j][r] * scale + mv;
    }
    #pragma unroll
    for (int r = 0; r < 4; ++r) {
      float tm = fmaxf(fmaxf(sarr[0][r], sarr[1][r]), fmaxf(sarr[2][r], sarr[3][r]));
      #pragma unroll
      for (int d = 1; d < 16; d <<= 1) tm = fmaxf(tm, __shfl_xor(tm, d));
      float mnew = fmaxf(mrun[r], tm);
      float alpha = __expf(mrun[r] - mnew);
      mrun[r] = mnew;
      float rs = 0.f;
      #pragma unroll
      for (int j = 0; j < 4; ++j) {
        float p = __expf(sarr[j][r] - mnew);
        sarr[j][r] = p;
        rs += p;
      }
      #pragma unroll
      for (int d = 1; d < 16; d <<= 1) rs += __shfl_xor(rs, d);
      lrun[r] = lrun[r] * alpha + rs;
      #pragma unroll
      for (int n = 0; n < 8; ++n) o[n][r] *= alpha;
    }
    #pragma unroll
    for (int r = 0; r < 4; ++r) {
      int qr = lg * 4 + r;
      #pragma unroll
      for (int j = 0; j < 4; ++j)
        *reinterpret_cast<__hip_bfloat16*>(
            Ps[w] + ((qr * 128 + (j * 16 + lr) * 2) ^ ((qr & 7) << 4))) =
            __float2bfloat16(sarr[j][r]);
    }
    #pragma unroll
    for (int kk2 = 0; kk2 < 2; ++kk2) {
      short8 pa = *reinterpret_cast<const short8*>(
          Ps[w] + ((lr * 128 + kk2 * 64 + lg * 16) ^ ((lr & 7) << 4)));
      #pragma unroll
      for (int n = 0; n < 8; ++n) {
        int hd = n * 16 + lr;
        short8 vb = *reinterpret_cast<const short8*>(
            Vt[buf] + hd * 128 + (((kk2 * 4 + lg) ^ (hd & 7)) * 16));
        o[n] = __builtin_amdgcn_mfma_f32_16x16x32_bf16(pa, vb, o[n], 0, 0, 0);
      }
    }
    __syncthreads();
    buf ^= 1;
  }

  const int h = bh & 15;
  #pragma unroll
  for (int r = 0; r < 4; ++r) {
    float inv = 1.0f / lrun[r];
    int srow = qt * 128 + w * 16 + lg * 4 + r;
    __hip_bfloat16* cp = ctx + ((size_t)b * kS + srow) * kD + h * 128 + lr;
    #pragma unroll
    for (int n = 0; n < 8; ++n) cp[n * 16] = __float2bfloat16(o[n][r] * inv);
  }
}

// ------- LayerNorm over (p0 + p1 + bias + res), one 2048-row per block -------
template <bool WB16>
__global__ void ln_fuse(const float* __restrict__ p0, const float* __restrict__ p1,
                        const float* __restrict__ bias, const float* __restrict__ res,
                        const float* __restrict__ w, const float* __restrict__ b,
                        float* __restrict__ outf, __hip_bfloat16* __restrict__ outb) {
  const int row = blockIdx.x, tid = threadIdx.x;
  const size_t base = (size_t)row * kD;
  float v[8];
  #pragma unroll
  for (int i = 0; i < 2; ++i) {
    int c4 = tid * 2 + i;
    float4 a  = reinterpret_cast<const float4*>(p0 + base)[c4];
    float4 bb = reinterpret_cast<const float4*>(p1 + base)[c4];
    float4 rr = reinterpret_cast<const float4*>(res + base)[c4];
    float4 bs = reinterpret_cast<const float4*>(bias)[c4];
    v[i * 4 + 0] = a.x + bb.x + rr.x + bs.x;
    v[i * 4 + 1] = a.y + bb.y + rr.y + bs.y;
    v[i * 4 + 2] = a.z + bb.z + rr.z + bs.z;
    v[i * 4 + 3] = a.w + bb.w + rr.w + bs.w;
  }
  float s = 0.f;
  #pragma unroll
  for (int i = 0; i < 8; ++i) s += v[i];
  #pragma unroll
  for (int off = 32; off > 0; off >>= 1) s += __shfl_down(s, off);
  __shared__ float r1[4], r2[4];
  if ((tid & 63) == 0) r1[tid >> 6] = s;
  __syncthreads();
  float mean = (r1[0] + r1[1] + r1[2] + r1[3]) * (1.0f / kD);
  float qv = 0.f;
  #pragma unroll
  for (int i = 0; i < 8; ++i) { float d = v[i] - mean; qv += d * d; }
  #pragma unroll
  for (int off = 32; off > 0; off >>= 1) qv += __shfl_down(qv, off);
  if ((tid & 63) == 0) r2[tid >> 6] = qv;
  __syncthreads();
  float rstd = rsqrtf((r2[0] + r2[1] + r2[2] + r2[3]) * (1.0f / kD) + kEPS);
  #pragma unroll
  for (int i = 0; i < 8; ++i) {
    int col = tid * 8 + i;
    float ov = (v[i] - mean) * rstd * w[col] + b[col];
    outf[base + col] = ov;
    if constexpr (WB16) outb[base + col] = __float2bfloat16(ov);
  }
}

// ---------------- launcher ----------------
extern "C" void kernel_launch(void* const* d_in, const int* in_sizes, int n_in,
                              void* d_out, int out_size, void* d_ws, size_t ws_size,
                              hipStream_t stream) {
  (void)in_sizes; (void)n_in; (void)out_size;
  if (ws_size < WS_NEED) return;
  const float* x    = (const float*)d_in[0];
  const float* mask = (const float*)d_in[1];
  const float* wq   = (const float*)d_in[2];
  const float* bq   = (const float*)d_in[3];
  const float* wk   = (const float*)d_in[4];
  const float* bk   = (const float*)d_in[5];
  const float* wv   = (const float*)d_in[6];
  const float* bv   = (const float*)d_in[7];
  const float* wo   = (const float*)d_in[8];
  const float* bo   = (const float*)d_in[9];
  const float* l1w  = (const float*)d_in[10];
  const float* l1b  = (const float*)d_in[11];
  const float* wi   = (const float*)d_in[12];
  const float* bi   = (const float*)d_in[13];
  const float* wo2  = (const float*)d_in[14];
  const float* bo2  = (const float*)d_in[15];
  const float* l2w  = (const float*)d_in[16];
  const float* l2b  = (const float*)d_in[17];

  char* ws = (char*)d_ws;
  __hip_bfloat16* wqb  = (__hip_bfloat16*)(ws + OFF_WQ);   // fused QKV weight base
  __hip_bfloat16* wkb  = (__hip_bfloat16*)(ws + OFF_WK);
  __hip_bfloat16* wvb  = (__hip_bfloat16*)(ws + OFF_WV);
  __hip_bfloat16* wob  = (__hip_bfloat16*)(ws + OFF_WO);
  __hip_bfloat16* wib  = (__hip_bfloat16*)(ws + OFF_WI);
  __hip_bfloat16* wo2b = (__hip_bfloat16*)(ws + OFF_WO2);
  __hip_bfloat16* xb   = (__hip_bfloat16*)(ws + OFF_XB);
  __hip_bfloat16* qb   = (__hip_bfloat16*)(ws + OFF_Q);    // q/k/vt contiguous
  __hip_bfloat16* kb2  = (__hip_bfloat16*)(ws + OFF_K);
  __hip_bfloat16* vtb  = (__hip_bfloat16*)(ws + OFF_V);
  __hip_bfloat16* hb   = (__hip_bfloat16*)(ws + OFF_H);
  __hip_bfloat16* ctxb = (__hip_bfloat16*)(ws + OFF_CTX);
  __hip_bfloat16* a1b  = (__hip_bfloat16*)(ws + OFF_A1B);
  float* y1   = (float*)(ws + OFF_Y1);
  float* y2   = (float*)(ws + OFF_Y2);
  float* f2p  = (float*)(ws + OFF_WQ);   // FFN2 split-K partial 1 (32MB, weights dead)
  float* bqkv = (float*)(ws + OFF_Y2);   // 24KB concat bias; dead before Wo writes y2

  // fp32 -> bf16 conversions
  cvt_bf16<<<2048, 256, 0, stream>>>(x,   xb,   kM * kD / 4);
  cvt_bf16<<<1024, 256, 0, stream>>>(wq,  wqb,  kD * kD / 4);
  cvt_bf16<<<1024, 256, 0, stream>>>(wk,  wkb,  kD * kD / 4);
  cvt_bf16<<<1024, 256, 0, stream>>>(wv,  wvb,  kD * kD / 4);
  cvt_bf16<<<1024, 256, 0, stream>>>(wo,  wob,  kD * kD / 4);
  cvt_bf16<<<2048, 256, 0, stream>>>(wi,  wib,  kF * kD / 4);
  cvt_bf16<<<2048, 256, 0, stream>>>(wo2, wo2b, kF * kD / 4);
  // concat QKV bias into scratch
  hipMemcpyAsync(bqkv,          bq, kD * 4, hipMemcpyDeviceToDevice, stream);
  hipMemcpyAsync(bqkv + kD,     bk, kD * 4, hipMemcpyDeviceToDevice, stream);
  hipMemcpyAsync(bqkv + 2 * kD, bv, kD * 4, hipMemcpyDeviceToDevice, stream);

  dim3 blk(512);
  // fused QKV projection: M=4096, N=6144, K=2048 -> grid 24*16 = 384
  gemm256<0><<<dim3(384), blk, 0, stream>>>(
      xb, wqb, bqkv, nullptr, nullptr, qb, kM, 6144, kD, kD);
  // attention
  attn_fwd<<<dim3(512), dim3(512), 0, stream>>>(qb, kb2, vtb, mask, ctxb);
  // out proj, split-K x2 (grid 2*8*16 = 256), partials y1,y2; LN1 fuses +bo+x
  gemm256<3><<<dim3(256), blk, 0, stream>>>(
      ctxb, wob, nullptr, y1, y2, nullptr, kM, kD, kD, kD / 2);
  ln_fuse<true><<<kM, 256, 0, stream>>>(y1, y2, bo, x, l1w, l1b, y1, a1b);
  // FFN1: M=4096, N=8192, K=2048 -> grid 32*16 = 512, GELU epilogue
  gemm256<2><<<dim3(512), blk, 0, stream>>>(
      a1b, wib, bi, nullptr, nullptr, hb, kM, kF, kD, kD);
  // FFN2: split-K x2 (grid 256), partials y2,f2p; LN2 fuses +bo2+attn_out(y1)
  gemm256<3><<<dim3(256), blk, 0, stream>>>(
      hb, wo2b, nullptr, y2, f2p, nullptr, kM, kD, kF, kF / 2);
  ln_fuse<false><<<kM, 256, 0, stream>>>(y2, f2p, bo2, y1, l2w, l2b, (float*)d_out, nullptr);
}

// Round 6
// 666.566 us; speedup vs baseline: 1.3575x; 1.0335x over previous
//
#include <hip/hip_runtime.h>
#include <hip/hip_bf16.h>
#include <cstdint>
#include <cstddef>

typedef __attribute__((ext_vector_type(8))) short short8;   // 8 x bf16 (4 VGPRs)
typedef __attribute__((ext_vector_type(4))) float f32x4;    // MFMA accumulator

#define DEV static __device__ __forceinline__

constexpr int kS = 1024, kD = 2048, kH = 16, kHD = 128, kF = 8192;
constexpr int kM = 4096;            // B*S rows
constexpr float kEPS = 1e-5f;

// ---------------- workspace layout (bytes) ----------------
constexpr size_t SZ_DD   = (size_t)kD * kD * 2;    // 8 MB   bf16 DxD weight
constexpr size_t SZ_FD   = (size_t)kF * kD * 2;    // 32 MB  bf16 FxD weight
constexpr size_t SZ_MD16 = (size_t)kM * kD * 2;    // 16 MB  bf16 activation
constexpr size_t SZ_MD32 = (size_t)kM * kD * 4;    // 32 MB  f32 activation
constexpr size_t OFF_WQ  = 0;                      // wq/wk/wv contiguous => fused QKV weight
constexpr size_t OFF_WK  = OFF_WQ + SZ_DD;
constexpr size_t OFF_WV  = OFF_WK + SZ_DD;
constexpr size_t OFF_WO  = OFF_WV + SZ_DD;
constexpr size_t OFF_WI  = OFF_WO + SZ_DD;
constexpr size_t OFF_WO2 = OFF_WI + SZ_FD;
constexpr size_t OFF_XB  = OFF_WO2 + SZ_FD;        // region reused for h later
constexpr size_t OFF_Q   = OFF_XB + SZ_MD16;       // q/k/vt contiguous (fused epilogue)
constexpr size_t OFF_K   = OFF_Q + SZ_MD16;
constexpr size_t OFF_V   = OFF_K + SZ_MD16;        // holds V^T layout [bh][hd][s]
constexpr size_t OFF_H   = OFF_XB;                 // 64 MB: xb+q+k+v dead by FFN1
constexpr size_t OFF_CTX = OFF_V + SZ_MD16;
constexpr size_t OFF_Y1  = OFF_CTX + SZ_MD16;      // f32
constexpr size_t OFF_A1B = OFF_Y1 + SZ_MD32;       // bf16 attn_out
constexpr size_t OFF_Y2  = OFF_A1B + SZ_MD16;      // f32 (first 24KB doubles as bqkv early)
constexpr size_t WS_NEED = OFF_Y2 + SZ_MD32;       // 256 MB total
// FFN2 second split-K partial reuses dead wq..wo region (4 x 8MB = 32MB) at OFF_WQ.

DEV void gload16(const void* g, void* l) {
  __builtin_amdgcn_global_load_lds(
      (const __attribute__((address_space(1))) unsigned int*)g,
      (__attribute__((address_space(3))) unsigned int*)l, 16, 0, 0);
}

// ---------------- fp32 -> bf16 convert ----------------
__global__ void cvt_bf16(const float* __restrict__ in, __hip_bfloat16* __restrict__ out, int n4) {
  int stride = gridDim.x * blockDim.x;
  for (int i = blockIdx.x * blockDim.x + threadIdx.x; i < n4; i += stride) {
    float4 v = reinterpret_cast<const float4*>(in)[i];
    union { ushort4 u; __hip_bfloat16 h[4]; } o;
    o.h[0] = __float2bfloat16(v.x);
    o.h[1] = __float2bfloat16(v.y);
    o.h[2] = __float2bfloat16(v.z);
    o.h[3] = __float2bfloat16(v.w);
    reinterpret_cast<ushort4*>(out)[i] = o.u;
  }
}

// ---------------- 256x256 overlapped-pipeline GEMM, 2 K-tiles/iter ----------------
// C = A[MxK] * Bt[NxK]^T. BK=64, 8 waves 2x4 inside one 128x128 C-quadrant.
// Quad walk M0N0 -> M0N1 -> M1N1 -> M1N0 (adjacent phases share one operand;
// only B0 re-read at P3). ONE barrier per phase (vmcnt-wait + s_barrier at
// phase START = cross-wave staging-visibility fence), NO barrier at P3 —
// wave skew overlaps MFMA with other waves' ds_reads. Counted lgkmcnt inside
// each phase: kk=0 MFMA group runs while kk=1 ds_reads complete.
// Stage order per tile: A0,B0,B1,A1 of t+1 at P0..P3; steady waits vmcnt(4)
// (waited halves >=3 phases old); tail 4/2/0.
// MODE 0: fused QKV scatter (q/k -> [b,h,s,hd], v -> [b,h,hd,s]), outb = q base
// MODE 2: out bf16 = gelu(acc + bias) at [row*N+col], outb
// MODE 3: raw f32 partial (split-K): out0/out1 selected by split index
template <int MODE>
__global__ __launch_bounds__(512, 2)
void gemm256(const __hip_bfloat16* __restrict__ A,
             const __hip_bfloat16* __restrict__ Bt,
             const float* __restrict__ bias,
             float* __restrict__ out0, float* __restrict__ out1,
             void* __restrict__ outb,
             int M, int N, int K, int kLen) {
  __shared__ __align__(16) char lds[131072];   // A: [2][256][64]b16 @0, B: @65536
  const int tid = threadIdx.x;
  const int lane = tid & 63, w = tid >> 6;
  const int wm = w >> 2, wn = w & 3;           // 2x4 waves inside a 128x128 quadrant
  const int lg = lane >> 4, lr = lane & 15;
  const int gy = M >> 8, gx = N >> 8;
  const int nwg = gridDim.x, orig = blockIdx.x;
  const int l = (orig & 7) * (nwg >> 3) + (orig >> 3);   // XCD-chunked (nwg%8==0)
  const int tilesPer = gx * gy;
  const int spl = l / tilesPer;
  const int rem = l - spl * tilesPer;
  const int bx = rem / gy, by = rem - bx * gy;           // n-panel-major
  const int m0 = by * 256, n0 = bx * 256;
  const int k0 = spl * kLen;
  const int NT = kLen >> 6;                               // even for all our shapes

  // staging source pointers (half 0=A0,1=A1,2=B0,3=B1; i 0..1), tile-0 based
  const char* gs[8];
  #pragma unroll
  for (int h = 0; h < 4; ++h) {
    const __hip_bfloat16* src = (h < 2) ? A : Bt;
    const int r0 = ((h < 2) ? m0 : n0) + (h & 1) * 128;
    #pragma unroll
    for (int i = 0; i < 2; ++i) {
      int c = i * 512 + tid;
      int row = c >> 3, slot = c & 7;
      gs[h * 2 + i] =
          (const char*)(src + (size_t)(r0 + row) * K + k0 + (slot ^ (row & 7)) * 8);
    }
  }

#define STAGE(P, H, TOFF)                                                          \
  {                                                                                \
    char* dstb = lds + (((H) < 2) ? 0 : 65536) + (P) * 32768 + ((H) & 1) * 16384;  \
    gload16(gs[(H) * 2 + 0] + (TOFF) * 128, dstb + (0 * 512 + tid) * 16);          \
    gload16(gs[(H) * 2 + 1] + (TOFF) * 128, dstb + (1 * 512 + tid) * 16);          \
  }

  auto ldA = [&](int P, int qm, int mr, int kk) {
    int row = qm * 128 + wm * 64 + mr * 16 + lr;
    return *reinterpret_cast<const short8*>(
        lds + P * 32768 + row * 128 + (((kk * 4 + lg) ^ (row & 7)) * 16));
  };
  auto ldB = [&](int P, int qn, int nr, int kk) {
    int row = qn * 128 + wn * 32 + nr * 16 + lr;
    return *reinterpret_cast<const short8*>(
        lds + 65536 + P * 32768 + row * 128 + (((kk * 4 + lg) ^ (row & 7)) * 16));
  };

  f32x4 acc[4][4][2] = {};   // [phase-quad][mi][ni]

#define MFMA_HALF(q, kk)                                                        \
  _Pragma("unroll")                                                             \
  for (int mi = 0; mi < 4; ++mi)                                                \
    _Pragma("unroll")                                                           \
    for (int ni = 0; ni < 2; ++ni)                                              \
      acc[q][mi][ni] = __builtin_amdgcn_mfma_f32_16x16x32_bf16(                 \
          av[kk][mi], bv[kk][ni], acc[q][mi][ni], 0, 0, 0);

// One K-tile; P = literal buffer parity, PF = prefetch next tile (TOFF = 1+P).
// Quads: q0=(M0,N0) q1=(M0,N1) q2=(M1,N1) q3=(M1,N0).
#define TILE_BODY(P, PF)                                                        \
  {                                                                             \
    /* P0: q0 — wait+fence A0,B0(t); read av=A0,bv=B0; stage A0(next) */        \
    asm volatile("s_waitcnt vmcnt(4)" ::: "memory");                            \
    __builtin_amdgcn_s_barrier();                                               \
    _Pragma("unroll")                                                           \
    for (int i = 0; i < 4; ++i) av[0][i] = ldA(P, 0, i, 0);                     \
    _Pragma("unroll")                                                           \
    for (int i = 0; i < 2; ++i) bv[0][i] = ldB(P, 0, i, 0);                     \
    _Pragma("unroll")                                                           \
    for (int i = 0; i < 4; ++i) av[1][i] = ldA(P, 0, i, 1);                     \
    _Pragma("unroll")                                                           \
    for (int i = 0; i < 2; ++i) bv[1][i] = ldB(P, 0, i, 1);                     \
    if (PF) STAGE((P) ^ 1, 0, 1 + (P));                                         \
    asm volatile("s_waitcnt lgkmcnt(6)" ::: "memory");                          \
    __builtin_amdgcn_sched_barrier(0);                                          \
    __builtin_amdgcn_s_setprio(1);                                              \
    MFMA_HALF(0, 0)                                                             \
    asm volatile("s_waitcnt lgkmcnt(0)" ::: "memory");                          \
    __builtin_amdgcn_sched_barrier(0);                                          \
    MFMA_HALF(0, 1)                                                             \
    __builtin_amdgcn_s_setprio(0);                                              \
    /* P1: q1 — wait+fence B1(t); read bv=B1; stage B0(next); reuse av */       \
    if (PF) { asm volatile("s_waitcnt vmcnt(4)" ::: "memory"); }                \
    else    { asm volatile("s_waitcnt vmcnt(2)" ::: "memory"); }                \
    __builtin_amdgcn_s_barrier();                                               \
    _Pragma("unroll")                                                           \
    for (int i = 0; i < 2; ++i) bv[0][i] = ldB(P, 1, i, 0);                     \
    _Pragma("unroll")                                                           \
    for (int i = 0; i < 2; ++i) bv[1][i] = ldB(P, 1, i, 1);                     \
    if (PF) STAGE((P) ^ 1, 2, 1 + (P));                                         \
    asm volatile("s_waitcnt lgkmcnt(2)" ::: "memory");                          \
    __builtin_amdgcn_sched_barrier(0);                                          \
    __builtin_amdgcn_s_setprio(1);                                              \
    MFMA_HALF(1, 0)                                                             \
    asm volatile("s_waitcnt lgkmcnt(0)" ::: "memory");                          \
    __builtin_amdgcn_sched_barrier(0);                                          \
    MFMA_HALF(1, 1)                                                             \
    __builtin_amdgcn_s_setprio(0);                                              \
    /* P2: q2 — wait+fence A1(t); read av=A1; stage B1(next); reuse bv */       \
    if (PF) { asm volatile("s_waitcnt vmcnt(4)" ::: "memory"); }                \
    else    { asm volatile("s_waitcnt vmcnt(0)" ::: "memory"); }                \
    __builtin_amdgcn_s_barrier();                                               \
    _Pragma("unroll")                                                           \
    for (int i = 0; i < 4; ++i) av[0][i] = ldA(P, 1, i, 0);                     \
    _Pragma("unroll")                                                           \
    for (int i = 0; i < 4; ++i) av[1][i] = ldA(P, 1, i, 1);                     \
    if (PF) STAGE((P) ^ 1, 3, 1 + (P));                                         \
    asm volatile("s_waitcnt lgkmcnt(4)" ::: "memory");                          \
    __builtin_amdgcn_sched_barrier(0);                                          \
    __builtin_amdgcn_s_setprio(1);                                              \
    MFMA_HALF(2, 0)                                                             \
    asm volatile("s_waitcnt lgkmcnt(0)" ::: "memory");                          \
    __builtin_amdgcn_sched_barrier(0);                                          \
    MFMA_HALF(2, 1)                                                             \
    __builtin_amdgcn_s_setprio(0);                                              \
    /* P3: q3 — no wait, NO barrier; re-read bv=B0; stage A1(next); reuse av */ \
    _Pragma("unroll")                                                           \
    for (int i = 0; i < 2; ++i) bv[0][i] = ldB(P, 0, i, 0);                     \
    _Pragma("unroll")                                                           \
    for (int i = 0; i < 2; ++i) bv[1][i] = ldB(P, 0, i, 1);                     \
    if (PF) STAGE((P) ^ 1, 1, 1 + (P));                                         \
    asm volatile("s_waitcnt lgkmcnt(2)" ::: "memory");                          \
    __builtin_amdgcn_sched_barrier(0);                                          \
    __builtin_amdgcn_s_setprio(1);                                              \
    MFMA_HALF(3, 0)                                                             \
    asm volatile("s_waitcnt lgkmcnt(0)" ::: "memory");                          \
    __builtin_amdgcn_sched_barrier(0);                                          \
    MFMA_HALF(3, 1)                                                             \
    __builtin_amdgcn_s_setprio(0);                                              \
  }

  // prologue: stage tile 0's halves in consumption order A0,B0,B1,A1
  STAGE(0, 0, 0) STAGE(0, 2, 0) STAGE(0, 3, 0) STAGE(0, 1, 0)

  for (int t2 = 0; t2 < NT; t2 += 2) {
    short8 av[2][4], bv[2][2];
    TILE_BODY(0, true)
    TILE_BODY(1, (t2 + 2 < NT))
    #pragma unroll
    for (int j = 0; j < 8; ++j) gs[j] += 256;
  }
#undef TILE_BODY
#undef MFMA_HALF
#undef STAGE

  // epilogue: q0=(0,0) q1=(0,1) q2=(1,1) q3=(1,0)
  #pragma unroll
  for (int q = 0; q < 4; ++q) {
    const int qm = (q >= 2) ? 1 : 0;
    const int qn = (q == 1 || q == 2) ? 1 : 0;
    #pragma unroll
    for (int ni = 0; ni < 2; ++ni) {
      int col = n0 + qn * 128 + wn * 32 + ni * 16 + lr;
      float bvv = 0.f;
      if constexpr (MODE != 3) bvv = bias[col];
      #pragma unroll
      for (int mi = 0; mi < 4; ++mi) {
        int row0 = m0 + qm * 128 + wm * 64 + mi * 16 + lg * 4;
        #pragma unroll
        for (int r = 0; r < 4; ++r) {
          int row = row0 + r;
          float val = acc[q][mi][ni][r] + bvv;
          if constexpr (MODE == 0) {
            int which = col >> 11;                  // 0=q 1=k 2=v
            int d = col & 2047;
            int hh = d >> 7, hd = d & 127;
            int bb = row >> 10, ss = row & 1023;
            __hip_bfloat16* base = (__hip_bfloat16*)outb + (size_t)which * ((size_t)kM * kD);
            if (which < 2)
              base[(((size_t)(bb * kH + hh)) * kS + ss) * kHD + hd] = __float2bfloat16(val);
            else
              base[(((size_t)(bb * kH + hh)) * kHD + hd) * kS + ss] = __float2bfloat16(val);
          } else if constexpr (MODE == 2) {
            float g = 0.5f * val * (1.0f + erff(val * 0.70710678118654752f));
            ((__hip_bfloat16*)outb)[(size_t)row * N + col] = __float2bfloat16(g);
          } else {
            float* o = spl ? out1 : out0;
            o[(size_t)row * N + col] = val;
          }
        }
      }
    }
  }
}

// ---------------- flash attention (unchanged) ----------------
__global__ __launch_bounds__(512, 4)
void attn_fwd(const __hip_bfloat16* __restrict__ q,
              const __hip_bfloat16* __restrict__ k,
              const __hip_bfloat16* __restrict__ vt,
              const float* __restrict__ mask,
              __hip_bfloat16* __restrict__ ctx) {
  __shared__ __align__(16) char Ks[2][64 * 256];    // [buf][key][dim] slot16^(row&15)
  __shared__ __align__(16) char Vt[2][128 * 128];   // [buf][hd][key64] slot8^(row&7)
  __shared__ __align__(16) char Ps[8][2048];        // per-wave P [16][64], ^((row&7)<<4)
  const int tid = threadIdx.x, lane = tid & 63, w = tid >> 6;
  const int lg = lane >> 4, lr = lane & 15;
  const int orig = blockIdx.x;                      // 512 blocks
  const int l = (orig & 7) * 64 + (orig >> 3);      // XCD-chunked: 8 bh per XCD
  const int qt = l & 7, bh = l >> 3;
  const int b = bh >> 4;

  short8 qf[4];
  {
    const __hip_bfloat16* qp =
        q + ((size_t)bh * kS + qt * 128 + w * 16 + lr) * kHD + lg * 8;
    #pragma unroll
    for (int kk = 0; kk < 4; ++kk) qf[kk] = *reinterpret_cast<const short8*>(qp + kk * 32);
  }

  auto stage = [&](int bufi, int t) {
    #pragma unroll
    for (int i = 0; i < 2; ++i) {                   // K tile: 64 rows x 256B
      int c = i * 512 + tid;
      int row = c >> 4, slot = c & 15;
      gload16(k + ((size_t)bh * kS + t * 64 + row) * kHD + (slot ^ (row & 15)) * 8,
              Ks[bufi] + c * 16);
    }
    #pragma unroll
    for (int i = 0; i < 2; ++i) {                   // V^T tile: 128 rows x 128B
      int c = i * 512 + tid;
      int row = c >> 3, slot = c & 7;
      gload16(vt + ((size_t)bh * kHD + row) * kS + t * 64 + (slot ^ (row & 7)) * 8,
              Vt[bufi] + c * 16);
    }
  };

  f32x4 o[8] = {};
  float mrun[4], lrun[4];
  #pragma unroll
  for (int r = 0; r < 4; ++r) { mrun[r] = -1e30f; lrun[r] = 0.f; }
  const float scale = 0.08838834764831845f;         // 1/sqrt(128)

  stage(0, 0);
  __syncthreads();

  int buf = 0;
  for (int t = 0; t < 16; ++t) {
    if (t + 1 < 16) stage(buf ^ 1, t + 1);

    f32x4 sacc[4] = {};
    #pragma unroll
    for (int j = 0; j < 4; ++j) {
      int key = j * 16 + lr;
      #pragma unroll
      for (int kk = 0; kk < 4; ++kk) {
        short8 bfrag = *reinterpret_cast<const short8*>(
            Ks[buf] + key * 256 + (((kk * 4 + lg) ^ (key & 15)) * 16));
        sacc[j] = __builtin_amdgcn_mfma_f32_16x16x32_bf16(qf[kk], bfrag, sacc[j], 0, 0, 0);
      }
    }
    float sarr[4][4];
    #pragma unroll
    for (int j = 0; j < 4; ++j) {
      float mv = mask[(size_t)b * kS + t * 64 + j * 16 + lr];
      #pragma unroll
      for (int r = 0; r < 4; ++r) sarr[j][r] = sacc[j][r] * scale + mv;
    }
    #pragma unroll
    for (int r = 0; r < 4; ++r) {
      float tm = fmaxf(fmaxf(sarr[0][r], sarr[1][r]), fmaxf(sarr[2][r], sarr[3][r]));
      #pragma unroll
      for (int d = 1; d < 16; d <<= 1) tm = fmaxf(tm, __shfl_xor(tm, d));
      float mnew = fmaxf(mrun[r], tm);
      float alpha = __expf(mrun[r] - mnew);
      mrun[r] = mnew;
      float rs = 0.f;
      #pragma unroll
      for (int j = 0; j < 4; ++j) {
        float p = __expf(sarr[j][r] - mnew);
        sarr[j][r] = p;
        rs += p;
      }
      #pragma unroll
      for (int d = 1; d < 16; d <<= 1) rs += __shfl_xor(rs, d);
      lrun[r] = lrun[r] * alpha + rs;
      #pragma unroll
      for (int n = 0; n < 8; ++n) o[n][r] *= alpha;
    }
    #pragma unroll
    for (int r = 0; r < 4; ++r) {
      int qr = lg * 4 + r;
      #pragma unroll
      for (int j = 0; j < 4; ++j)
        *reinterpret_cast<__hip_bfloat16*>(
            Ps[w] + ((qr * 128 + (j * 16 + lr) * 2) ^ ((qr & 7) << 4))) =
            __float2bfloat16(sarr[j][r]);
    }
    #pragma unroll
    for (int kk2 = 0; kk2 < 2; ++kk2) {
      short8 pa = *reinterpret_cast<const short8*>(
          Ps[w] + ((lr * 128 + kk2 * 64 + lg * 16) ^ ((lr & 7) << 4)));
      #pragma unroll
      for (int n = 0; n < 8; ++n) {
        int hd = n * 16 + lr;
        short8 vb = *reinterpret_cast<const short8*>(
            Vt[buf] + hd * 128 + (((kk2 * 4 + lg) ^ (hd & 7)) * 16));
        o[n] = __builtin_amdgcn_mfma_f32_16x16x32_bf16(pa, vb, o[n], 0, 0, 0);
      }
    }
    __syncthreads();
    buf ^= 1;
  }

  const int h = bh & 15;
  #pragma unroll
  for (int r = 0; r < 4; ++r) {
    float inv = 1.0f / lrun[r];
    int srow = qt * 128 + w * 16 + lg * 4 + r;
    __hip_bfloat16* cp = ctx + ((size_t)b * kS + srow) * kD + h * 128 + lr;
    #pragma unroll
    for (int n = 0; n < 8; ++n) cp[n * 16] = __float2bfloat16(o[n][r] * inv);
  }
}

// ------- LayerNorm over (p0 + p1 + bias + res), one 2048-row per block -------
template <bool WB16>
__global__ void ln_fuse(const float* __restrict__ p0, const float* __restrict__ p1,
                        const float* __restrict__ bias, const float* __restrict__ res,
                        const float* __restrict__ w, const float* __restrict__ b,
                        float* __restrict__ outf, __hip_bfloat16* __restrict__ outb) {
  const int row = blockIdx.x, tid = threadIdx.x;
  const size_t base = (size_t)row * kD;
  float v[8];
  #pragma unroll
  for (int i = 0; i < 2; ++i) {
    int c4 = tid * 2 + i;
    float4 a  = reinterpret_cast<const float4*>(p0 + base)[c4];
    float4 bb = reinterpret_cast<const float4*>(p1 + base)[c4];
    float4 rr = reinterpret_cast<const float4*>(res + base)[c4];
    float4 bs = reinterpret_cast<const float4*>(bias)[c4];
    v[i * 4 + 0] = a.x + bb.x + rr.x + bs.x;
    v[i * 4 + 1] = a.y + bb.y + rr.y + bs.y;
    v[i * 4 + 2] = a.z + bb.z + rr.z + bs.z;
    v[i * 4 + 3] = a.w + bb.w + rr.w + bs.w;
  }
  float s = 0.f;
  #pragma unroll
  for (int i = 0; i < 8; ++i) s += v[i];
  #pragma unroll
  for (int off = 32; off > 0; off >>= 1) s += __shfl_down(s, off);
  __shared__ float r1[4], r2[4];
  if ((tid & 63) == 0) r1[tid >> 6] = s;
  __syncthreads();
  float mean = (r1[0] + r1[1] + r1[2] + r1[3]) * (1.0f / kD);
  float qv = 0.f;
  #pragma unroll
  for (int i = 0; i < 8; ++i) { float d = v[i] - mean; qv += d * d; }
  #pragma unroll
  for (int off = 32; off > 0; off >>= 1) qv += __shfl_down(qv, off);
  if ((tid & 63) == 0) r2[tid >> 6] = qv;
  __syncthreads();
  float rstd = rsqrtf((r2[0] + r2[1] + r2[2] + r2[3]) * (1.0f / kD) + kEPS);
  #pragma unroll
  for (int i = 0; i < 8; ++i) {
    int col = tid * 8 + i;
    float ov = (v[i] - mean) * rstd * w[col] + b[col];
    outf[base + col] = ov;
    if constexpr (WB16) outb[base + col] = __float2bfloat16(ov);
  }
}

// ---------------- launcher ----------------
extern "C" void kernel_launch(void* const* d_in, const int* in_sizes, int n_in,
                              void* d_out, int out_size, void* d_ws, size_t ws_size,
                              hipStream_t stream) {
  (void)in_sizes; (void)n_in; (void)out_size;
  if (ws_size < WS_NEED) return;
  const float* x    = (const float*)d_in[0];
  const float* mask = (const float*)d_in[1];
  const float* wq   = (const float*)d_in[2];
  const float* bq   = (const float*)d_in[3];
  const float* wk   = (const float*)d_in[4];
  const float* bk   = (const float*)d_in[5];
  const float* wv   = (const float*)d_in[6];
  const float* bv   = (const float*)d_in[7];
  const float* wo   = (const float*)d_in[8];
  const float* bo   = (const float*)d_in[9];
  const float* l1w  = (const float*)d_in[10];
  const float* l1b  = (const float*)d_in[11];
  const float* wi   = (const float*)d_in[12];
  const float* bi   = (const float*)d_in[13];
  const float* wo2  = (const float*)d_in[14];
  const float* bo2  = (const float*)d_in[15];
  const float* l2w  = (const float*)d_in[16];
  const float* l2b  = (const float*)d_in[17];

  char* ws = (char*)d_ws;
  __hip_bfloat16* wqb  = (__hip_bfloat16*)(ws + OFF_WQ);   // fused QKV weight base
  __hip_bfloat16* wkb  = (__hip_bfloat16*)(ws + OFF_WK);
  __hip_bfloat16* wvb  = (__hip_bfloat16*)(ws + OFF_WV);
  __hip_bfloat16* wob  = (__hip_bfloat16*)(ws + OFF_WO);
  __hip_bfloat16* wib  = (__hip_bfloat16*)(ws + OFF_WI);
  __hip_bfloat16* wo2b = (__hip_bfloat16*)(ws + OFF_WO2);
  __hip_bfloat16* xb   = (__hip_bfloat16*)(ws + OFF_XB);
  __hip_bfloat16* qb   = (__hip_bfloat16*)(ws + OFF_Q);    // q/k/vt contiguous
  __hip_bfloat16* kb2  = (__hip_bfloat16*)(ws + OFF_K);
  __hip_bfloat16* vtb  = (__hip_bfloat16*)(ws + OFF_V);
  __hip_bfloat16* hb   = (__hip_bfloat16*)(ws + OFF_H);
  __hip_bfloat16* ctxb = (__hip_bfloat16*)(ws + OFF_CTX);
  __hip_bfloat16* a1b  = (__hip_bfloat16*)(ws + OFF_A1B);
  float* y1   = (float*)(ws + OFF_Y1);
  float* y2   = (float*)(ws + OFF_Y2);
  float* f2p  = (float*)(ws + OFF_WQ);   // FFN2 split-K partial 1 (32MB, weights dead)
  float* bqkv = (float*)(ws + OFF_Y2);   // 24KB concat bias; dead before Wo writes y2

  // fp32 -> bf16 conversions
  cvt_bf16<<<2048, 256, 0, stream>>>(x,   xb,   kM * kD / 4);
  cvt_bf16<<<1024, 256, 0, stream>>>(wq,  wqb,  kD * kD / 4);
  cvt_bf16<<<1024, 256, 0, stream>>>(wk,  wkb,  kD * kD / 4);
  cvt_bf16<<<1024, 256, 0, stream>>>(wv,  wvb,  kD * kD / 4);
  cvt_bf16<<<1024, 256, 0, stream>>>(wo,  wob,  kD * kD / 4);
  cvt_bf16<<<2048, 256, 0, stream>>>(wi,  wib,  kF * kD / 4);
  cvt_bf16<<<2048, 256, 0, stream>>>(wo2, wo2b, kF * kD / 4);
  // concat QKV bias into scratch
  hipMemcpyAsync(bqkv,          bq, kD * 4, hipMemcpyDeviceToDevice, stream);
  hipMemcpyAsync(bqkv + kD,     bk, kD * 4, hipMemcpyDeviceToDevice, stream);
  hipMemcpyAsync(bqkv + 2 * kD, bv, kD * 4, hipMemcpyDeviceToDevice, stream);

  dim3 blk(512);
  // fused QKV projection: M=4096, N=6144, K=2048 -> grid 24*16 = 384
  gemm256<0><<<dim3(384), blk, 0, stream>>>(
      xb, wqb, bqkv, nullptr, nullptr, qb, kM, 6144, kD, kD);
  // attention
  attn_fwd<<<dim3(512), dim3(512), 0, stream>>>(qb, kb2, vtb, mask, ctxb);
  // out proj, split-K x2 (grid 2*8*16 = 256), partials y1,y2; LN1 fuses +bo+x
  gemm256<3><<<dim3(256), blk, 0, stream>>>(
      ctxb, wob, nullptr, y1, y2, nullptr, kM, kD, kD, kD / 2);
  ln_fuse<true><<<kM, 256, 0, stream>>>(y1, y2, bo, x, l1w, l1b, y1, a1b);
  // FFN1: M=4096, N=8192, K=2048 -> grid 32*16 = 512, GELU epilogue
  gemm256<2><<<dim3(512), blk, 0, stream>>>(
      a1b, wib, bi, nullptr, nullptr, hb, kM, kF, kD, kD);
  // FFN2: split-K x2 (grid 256), partials y2,f2p; LN2 fuses +bo2+attn_out(y1)
  gemm256<3><<<dim3(256), blk, 0, stream>>>(
      hb, wo2b, nullptr, y2, f2p, nullptr, kM, kD, kF, kF / 2);
  ln_fuse<false><<<kM, 256, 0, stream>>>(y2, f2p, bo2, y1, l2w, l2b, (float*)d_out, nullptr);
}